// Round 1
// baseline (494.890 us; speedup 1.0000x reference)
//
#include <hip/hip_runtime.h>
#include <math.h>

constexpr int kN = 4096;
constexpr int kM = 4100;
constexpr int kD = 256;
constexpr int ROWCAP = 64;
constexpr int COLCAP = 64;
constexpr int BIGCAP = 2560;
constexpr float kLnEps = 1e-5f;
constexpr float kScale = 0.17677669529663687f; // 1/sqrt(32)

__device__ __forceinline__ float waveSum(float v) {
#pragma unroll
  for (int m = 32; m >= 1; m >>= 1) v += __shfl_xor(v, m);
  return v;
}
__device__ __forceinline__ float waveMax(float v) {
#pragma unroll
  for (int m = 32; m >= 1; m >>= 1) v = fmaxf(v, __shfl_xor(v, m));
  return v;
}
// 256-thread block sum; sh must be float[4] shared
__device__ __forceinline__ float blockSum256(float v, float* sh) {
  v = waveSum(v);
  int lane = threadIdx.x & 63, w = threadIdx.x >> 6;
  __syncthreads();
  if (lane == 0) sh[w] = v;
  __syncthreads();
  return sh[0] + sh[1] + sh[2] + sh[3];
}

// ---------------- sparse build ----------------
// one wave per row: deterministic ballot-compaction CSR; atomic scatter to CSC
__global__ __launch_bounds__(256) void k_build_csr(
    const float* __restrict__ H, int* __restrict__ row_cnt, int* __restrict__ row_idx,
    int* __restrict__ col_cnt, int* __restrict__ col_idx, float* __restrict__ col_val) {
  int n = (blockIdx.x * blockDim.x + threadIdx.x) >> 6;
  int lane = threadIdx.x & 63;
  const float* hrow = H + (size_t)n * kM;
  int cnt = 0;
  for (int m0 = 0; m0 < kM; m0 += 64) {
    int m = m0 + lane;
    float v = (m < kM) ? hrow[m] : 0.0f;
    unsigned long long bal = __ballot(v != 0.0f);
    if (v != 0.0f) {
      int pf = __popcll(bal & ((1ull << lane) - 1ull));
      int pos = cnt + pf;
      if (pos < ROWCAP) row_idx[n * ROWCAP + pos] = m;
      if (m < kN) {
        int pc = atomicAdd(&col_cnt[m], 1);
        if (pc < COLCAP) { col_idx[m * COLCAP + pc] = n; col_val[m * COLCAP + pc] = v; }
      }
    }
    cnt += __popcll(bal);
  }
  if (lane == 0) row_cnt[n] = cnt < ROWCAP ? cnt : ROWCAP;
}

// one wave per column: sort the (small) CSC list by row index -> deterministic order.
// deg is a sum of {1.0,2.0} values: integer-exact, order independent.
__global__ __launch_bounds__(256) void k_sort_csc(
    int* __restrict__ col_cnt, int* __restrict__ col_idx, float* __restrict__ col_val,
    float* __restrict__ deg) {
  int c = (blockIdx.x * blockDim.x + threadIdx.x) >> 6;
  int lane = threadIdx.x & 63;
  int cnt = col_cnt[c]; if (cnt > COLCAP) cnt = COLCAP;
  int iv = 0x7fffffff; float vv = 0.0f;
  if (lane < cnt) { iv = col_idx[c * COLCAP + lane]; vv = col_val[c * COLCAP + lane]; }
  float dsum = waveSum(vv);
  int rank = 0;
  for (int j = 0; j < 64; ++j) {
    int ivj = __shfl(iv, j);
    if (ivj < iv) rank++;
  }
  if (lane < cnt) { col_idx[c * COLCAP + rank] = iv; col_val[c * COLCAP + rank] = vv; }
  if (lane == 0) { deg[c] = dsum; col_cnt[c] = cnt; }
}

// deterministic build of the 4 dense (topo/stroma) columns; one wave per column
__global__ __launch_bounds__(256) void k_build_big(
    const float* __restrict__ H, int* __restrict__ big_cnt, int* __restrict__ big_idx,
    float* __restrict__ big_val, float* __restrict__ deg) {
  int w = threadIdx.x >> 6;
  int lane = threadIdx.x & 63;
  int m = kN + w;
  int cnt = 0; float ds = 0.0f;
  for (int i = 0; i < kN / 64; ++i) {
    int n = i * 64 + lane;
    float v = H[(size_t)n * kM + m];
    unsigned long long bal = __ballot(v != 0.0f);
    if (v != 0.0f) {
      int pf = __popcll(bal & ((1ull << lane) - 1ull));
      int pos = cnt + pf;
      if (pos < BIGCAP) { big_idx[w * BIGCAP + pos] = n; big_val[w * BIGCAP + pos] = v; }
    }
    cnt += __popcll(bal);
    ds += v;
  }
  ds = waveSum(ds);
  if (lane == 0) { big_cnt[w] = cnt < BIGCAP ? cnt : BIGCAP; deg[m] = ds; }
}

// ---------------- per-layer compute ----------------
__global__ __launch_bounds__(256) void k_ln(
    const float* __restrict__ X, float* __restrict__ Y,
    const float* __restrict__ g, const float* __restrict__ b) {
  __shared__ float sh[4];
  int n = blockIdx.x, d = threadIdx.x;
  float v = X[(size_t)n * kD + d];
  float mean = blockSum256(v, sh) * (1.0f / kD);
  float dv = v - mean;
  float var = blockSum256(dv * dv, sh) * (1.0f / kD);
  Y[(size_t)n * kD + d] = dv * rsqrtf(var + kLnEps) * g[d] + b[d];
}

// E row (m < kN) from sorted CSC, then LN -> En
__global__ __launch_bounds__(256) void k_e_small(
    const float* __restrict__ X, const int* __restrict__ col_cnt,
    const int* __restrict__ col_idx, const float* __restrict__ col_val,
    const float* __restrict__ deg, const float* __restrict__ g,
    const float* __restrict__ b, float* __restrict__ En) {
  __shared__ float sh[4];
  __shared__ int sidx[COLCAP];
  __shared__ float sval[COLCAP];
  int m = blockIdx.x, d = threadIdx.x;
  int cnt = col_cnt[m];
  if (d < cnt) { sidx[d] = col_idx[m * COLCAP + d]; sval[d] = col_val[m * COLCAP + d]; }
  __syncthreads();
  float s = 0.0f;
  for (int e = 0; e < cnt; ++e) s += sval[e] * X[(size_t)sidx[e] * kD + d];
  s *= (1.0f / deg[m]);
  float mean = blockSum256(s, sh) * (1.0f / kD);
  float dv = s - mean;
  float var = blockSum256(dv * dv, sh) * (1.0f / kD);
  En[(size_t)m * kD + d] = dv * rsqrtf(var + kLnEps) * g[d] + b[d];
}

constexpr int BIGCHUNK = 320;
__global__ __launch_bounds__(256) void k_e_big_part(
    const float* __restrict__ X, const int* __restrict__ big_cnt,
    const int* __restrict__ big_idx, const float* __restrict__ big_val,
    float* __restrict__ part) {
  __shared__ int sidx[BIGCHUNK];
  __shared__ float sval[BIGCHUNK];
  int c = blockIdx.y, chunk = blockIdx.x, d = threadIdx.x;
  int cnt = big_cnt[c];
  int e0 = chunk * BIGCHUNK;
  int e1 = min(cnt, e0 + BIGCHUNK);
  int ne = e1 - e0;
  for (int i = d; i < ne; i += 256) {
    sidx[i] = big_idx[c * BIGCAP + e0 + i];
    sval[i] = big_val[c * BIGCAP + e0 + i];
  }
  __syncthreads();
  float s = 0.0f;
  for (int e = 0; e < ne; ++e) s += sval[e] * X[(size_t)sidx[e] * kD + d];
  part[(size_t)(c * 8 + chunk) * kD + d] = s;
}

__global__ __launch_bounds__(256) void k_e_big_fin(
    const float* __restrict__ part, const float* __restrict__ deg,
    const float* __restrict__ g, const float* __restrict__ b, float* __restrict__ En) {
  __shared__ float sh[4];
  int c = blockIdx.x, d = threadIdx.x;
  float s = 0.0f;
#pragma unroll
  for (int k = 0; k < 8; ++k) s += part[(size_t)(c * 8 + k) * kD + d];
  s *= (1.0f / deg[kN + c]);
  float mean = blockSum256(s, sh) * (1.0f / kD);
  float dv = s - mean;
  float var = blockSum256(dv * dv, sh) * (1.0f / kD);
  En[(size_t)(kN + c) * kD + d] = dv * rsqrtf(var + kLnEps) * g[d] + b[d];
}

// C[n][o] = sum_k A[n][k]*W[o][k] + bias[o]; mode 1: 0.5*relu(.)+0.5*blend
__global__ __launch_bounds__(256) void k_gemm(
    const float* __restrict__ A, const float* __restrict__ W,
    const float* __restrict__ bias, float* __restrict__ C,
    const float* __restrict__ blend, int mode) {
  __shared__ __align__(16) float sA[32][68];
  __shared__ __align__(16) float sW[32][68];
  int t = threadIdx.x;
  int tx = t & 15, ty = t >> 4;
  int row0 = blockIdx.x * 64, col0 = blockIdx.y * 64;
  int kl = t & 31, nb = t >> 5;
  float acc[4][4] = {};
  for (int k0 = 0; k0 < kD; k0 += 32) {
#pragma unroll
    for (int i = 0; i < 8; ++i) {
      int nl = i * 8 + nb;
      sA[kl][nl] = A[(size_t)(row0 + nl) * kD + k0 + kl];
      sW[kl][nl] = W[(size_t)(col0 + nl) * kD + k0 + kl];
    }
    __syncthreads();
#pragma unroll
    for (int kk = 0; kk < 32; ++kk) {
      float4 av = *(const float4*)&sA[kk][ty * 4];
      float4 wv = *(const float4*)&sW[kk][tx * 4];
      acc[0][0] += av.x * wv.x; acc[0][1] += av.x * wv.y; acc[0][2] += av.x * wv.z; acc[0][3] += av.x * wv.w;
      acc[1][0] += av.y * wv.x; acc[1][1] += av.y * wv.y; acc[1][2] += av.y * wv.z; acc[1][3] += av.y * wv.w;
      acc[2][0] += av.z * wv.x; acc[2][1] += av.z * wv.y; acc[2][2] += av.z * wv.z; acc[2][3] += av.z * wv.w;
      acc[3][0] += av.w * wv.x; acc[3][1] += av.w * wv.y; acc[3][2] += av.w * wv.z; acc[3][3] += av.w * wv.w;
    }
    __syncthreads();
  }
  int cb = col0 + tx * 4;
  float4 bv = *(const float4*)&bias[cb];
#pragma unroll
  for (int i = 0; i < 4; ++i) {
    int r = row0 + ty * 4 + i;
    float4 v;
    v.x = acc[i][0] + bv.x; v.y = acc[i][1] + bv.y;
    v.z = acc[i][2] + bv.z; v.w = acc[i][3] + bv.w;
    if (mode == 1) {
      float4 x0 = *(const float4*)&blend[(size_t)r * kD + cb];
      v.x = 0.5f * fmaxf(v.x, 0.0f) + 0.5f * x0.x;
      v.y = 0.5f * fmaxf(v.y, 0.0f) + 0.5f * x0.y;
      v.z = 0.5f * fmaxf(v.z, 0.0f) + 0.5f * x0.z;
      v.w = 0.5f * fmaxf(v.w, 0.0f) + 0.5f * x0.w;
    }
    *(float4*)&C[(size_t)r * kD + cb] = v;
  }
}

// last 4 k-rows (topo: Wkt, stroma: Wks)
__global__ __launch_bounds__(256) void k_ktail(
    const float* __restrict__ En, const float* __restrict__ Wkt_w,
    const float* __restrict__ Wkt_b, const float* __restrict__ Wks_w,
    const float* __restrict__ Wks_b, float* __restrict__ K) {
  __shared__ float er[4][kD];
  int t = threadIdx.x;
  for (int i = t; i < 4 * kD; i += 256)
    er[i >> 8][i & 255] = En[(size_t)(kN + (i >> 8)) * kD + (i & 255)];
  __syncthreads();
  for (int r = 0; r < 4; ++r) {
    const float* W = (r < 3) ? Wkt_w : Wks_w;
    const float* B = (r < 3) ? Wkt_b : Wks_b;
    float acc = B[t];
    for (int dd = 0; dd < kD; ++dd) acc += er[r][dd] * W[(size_t)t * kD + dd];
    K[(size_t)(kN + r) * kD + t] = acc;
  }
}

// sparse masked attention: block per row, thread = (head h = t>>5, dim dd = t&31)
__global__ __launch_bounds__(256) void k_attn(
    const float* __restrict__ q, const float* __restrict__ kbuf,
    const int* __restrict__ row_cnt, const int* __restrict__ row_idx,
    float* __restrict__ featA) {
  __shared__ int sm[ROWCAP];
  __shared__ float sc[8][ROWCAP];
  int n = blockIdx.x, t = threadIdx.x;
  int h = t >> 5, dd = t & 31;
  int cnt = row_cnt[n];
  if (t < cnt) sm[t] = row_idx[n * ROWCAP + t];
  __syncthreads();
  float qv = q[(size_t)n * kD + t];
  for (int e = 0; e < cnt; ++e) {
    float kv = kbuf[(size_t)sm[e] * kD + t];
    float s = qv * kv;
#pragma unroll
    for (int mm = 16; mm >= 1; mm >>= 1) s += __shfl_xor(s, mm);
    if (dd == 0) sc[h][e] = s * kScale;
  }
  __syncthreads();
  float v1 = (dd < cnt) ? sc[h][dd] : -3.4e38f;
  float v2 = (dd + 32 < cnt) ? sc[h][dd + 32] : -3.4e38f;
  float mx = fmaxf(v1, v2);
#pragma unroll
  for (int mm = 16; mm >= 1; mm >>= 1) mx = fmaxf(mx, __shfl_xor(mx, mm));
  float p1 = (dd < cnt) ? expf(v1 - mx) : 0.0f;
  float p2 = (dd + 32 < cnt) ? expf(v2 - mx) : 0.0f;
  float ssum = p1 + p2;
#pragma unroll
  for (int mm = 16; mm >= 1; mm >>= 1) ssum += __shfl_xor(ssum, mm);
  float inv = 1.0f / ssum;
  if (dd < cnt) sc[h][dd] = p1 * inv;
  if (dd + 32 < cnt) sc[h][dd + 32] = p2 * inv;
  __syncthreads();
  float acc = 0.0f;
  for (int e = 0; e < cnt; ++e) acc += sc[h][e] * kbuf[(size_t)sm[e] * kD + t];
  featA[(size_t)n * kD + t] = acc;
}

// ---------------- pooling head ----------------
__global__ __launch_bounds__(256) void k_gate(
    const float* __restrict__ araw, const float* __restrict__ braw,
    const float* __restrict__ cw, const float* __restrict__ cb,
    float* __restrict__ Abuf) {
  __shared__ float sh[4];
  int n = blockIdx.x, o = threadIdx.x;
  float a = tanhf(araw[(size_t)n * kD + o]);
  float b = 1.0f / (1.0f + expf(-braw[(size_t)n * kD + o]));
  float s = blockSum256(a * b * cw[o], sh);
  if (o == 0) Abuf[n] = s + cb[0];
}

__global__ __launch_bounds__(256) void k_softmax_red(
    const float* __restrict__ Abuf, float* __restrict__ red) {
  __shared__ float sh[4];
  int t = threadIdx.x;
  float mx = -3.4e38f;
  for (int i = t; i < kN; i += 256) mx = fmaxf(mx, Abuf[i]);
  mx = waveMax(mx);
  int lane = t & 63, w = t >> 6;
  if (lane == 0) sh[w] = mx;
  __syncthreads();
  mx = fmaxf(fmaxf(sh[0], sh[1]), fmaxf(sh[2], sh[3]));
  __syncthreads();
  float s = 0.0f;
  for (int i = t; i < kN; i += 256) s += expf(Abuf[i] - mx);
  s = blockSum256(s, sh);
  if (t == 0) { red[0] = mx; red[1] = 1.0f / s; }
}

__global__ __launch_bounds__(256) void k_pool_part(
    const float* __restrict__ Abuf, const float* __restrict__ red,
    const float* __restrict__ feat, float* __restrict__ part) {
  int b = blockIdx.x, d = threadIdx.x;
  float mx = red[0], inv = red[1];
  float acc = 0.0f;
  for (int r = 0; r < 64; ++r) {
    int n = b * 64 + r;
    float p = expf(Abuf[n] - mx) * inv;
    acc += p * feat[(size_t)n * kD + d];
  }
  part[(size_t)b * kD + d] = acc;
}

__global__ __launch_bounds__(256) void k_pool_fin(
    const float* __restrict__ part, const float* __restrict__ out_w,
    const float* __restrict__ out_b, float* __restrict__ out) {
  __shared__ float pooled[kD];
  int d = threadIdx.x;
  float s = 0.0f;
#pragma unroll
  for (int b = 0; b < 64; ++b) s += part[(size_t)b * kD + d];
  pooled[d] = s;
  __syncthreads();
  if (d < 4) {
    float o = out_b[d];
    for (int i = 0; i < kD; ++i) o += pooled[i] * out_w[(size_t)d * kD + i];
    out[d] = o;
  }
}

extern "C" void kernel_launch(void* const* d_in, const int* in_sizes, int n_in,
                              void* d_out, int out_size, void* d_ws, size_t ws_size,
                              hipStream_t stream) {
  (void)in_sizes; (void)n_in; (void)out_size; (void)ws_size;
  const float* X     = (const float*)d_in[0];
  const float* H     = (const float*)d_in[1];
  const float* Wq_w  = (const float*)d_in[2];
  const float* Wq_b  = (const float*)d_in[3];
  const float* Wkn_w = (const float*)d_in[4];
  const float* Wkn_b = (const float*)d_in[5];
  const float* Wkt_w = (const float*)d_in[6];
  const float* Wkt_b = (const float*)d_in[7];
  const float* Wks_w = (const float*)d_in[8];
  const float* Wks_b = (const float*)d_in[9];
  const float* fc_w  = (const float*)d_in[10];
  const float* fc_b  = (const float*)d_in[11];
  const float* ln_g  = (const float*)d_in[12];
  const float* ln_b  = (const float*)d_in[13];
  const float* aw    = (const float*)d_in[14];
  const float* ab    = (const float*)d_in[15];
  const float* bw    = (const float*)d_in[16];
  const float* bb    = (const float*)d_in[17];
  const float* cw    = (const float*)d_in[18];
  const float* cb    = (const float*)d_in[19];
  const float* out_w = (const float*)d_in[20];
  const float* out_b = (const float*)d_in[21];

  char* p = (char*)d_ws;
  auto alloc = [&](size_t bytes) -> void* {
    void* r = (void*)p;
    p += (bytes + 255) & ~(size_t)255;
    return r;
  };
  int*   row_cnt = (int*)alloc(kN * 4);
  int*   row_idx = (int*)alloc((size_t)kN * ROWCAP * 4);
  int*   col_cnt = (int*)alloc(kN * 4);
  int*   col_idx = (int*)alloc((size_t)kN * COLCAP * 4);
  float* col_val = (float*)alloc((size_t)kN * COLCAP * 4);
  int*   big_cnt = (int*)alloc(4 * 4);
  int*   big_idx = (int*)alloc(4 * BIGCAP * 4);
  float* big_val = (float*)alloc(4 * BIGCAP * 4);
  float* deg     = (float*)alloc(kM * 4);
  float* Xn      = (float*)alloc((size_t)kN * kD * 4);
  float* En      = (float*)alloc((size_t)kM * kD * 4);
  float* qbuf    = (float*)alloc((size_t)kN * kD * 4);
  float* kbuf    = (float*)alloc((size_t)kM * kD * 4);
  float* featA   = (float*)alloc((size_t)kN * kD * 4);
  float* buf0    = (float*)alloc((size_t)kN * kD * 4);
  float* buf1    = (float*)alloc((size_t)kN * kD * 4);
  float* ebpart  = (float*)alloc(32 * kD * 4);
  float* Abuf    = (float*)alloc(kN * 4);
  float* red     = (float*)alloc(2 * 4);
  float* ppart   = (float*)alloc(64 * kD * 4);

  hipMemsetAsync(col_cnt, 0, kN * 4, stream);
  k_build_csr<<<kN / 4, 256, 0, stream>>>(H, row_cnt, row_idx, col_cnt, col_idx, col_val);
  k_sort_csc<<<kN / 4, 256, 0, stream>>>(col_cnt, col_idx, col_val, deg);
  k_build_big<<<1, 256, 0, stream>>>(H, big_cnt, big_idx, big_val, deg);

  for (int layer = 0; layer < 2; ++layer) {
    const float* Xc = layer ? buf0 : X;
    float* Xout = layer ? buf1 : buf0;
    size_t wo = (size_t)layer * kD * kD;
    size_t bo = (size_t)layer * kD;
    k_ln<<<kN, 256, 0, stream>>>(Xc, Xn, ln_g + bo, ln_b + bo);
    k_e_small<<<kN, 256, 0, stream>>>(Xc, col_cnt, col_idx, col_val, deg,
                                      ln_g + bo, ln_b + bo, En);
    k_e_big_part<<<dim3(8, 4), 256, 0, stream>>>(Xc, big_cnt, big_idx, big_val, ebpart);
    k_e_big_fin<<<4, 256, 0, stream>>>(ebpart, deg, ln_g + bo, ln_b + bo, En);
    k_gemm<<<dim3(64, 4), 256, 0, stream>>>(Xn, Wq_w + wo, Wq_b + bo, qbuf, nullptr, 0);
    k_gemm<<<dim3(64, 4), 256, 0, stream>>>(En, Wkn_w + wo, Wkn_b + bo, kbuf, nullptr, 0);
    k_ktail<<<1, 256, 0, stream>>>(En, Wkt_w + wo, Wkt_b + bo, Wks_w + wo, Wks_b + bo, kbuf);
    k_attn<<<kN, 256, 0, stream>>>(qbuf, kbuf, row_cnt, row_idx, featA);
    k_gemm<<<dim3(64, 4), 256, 0, stream>>>(featA, fc_w + wo, fc_b + bo, Xout, Xc, 1);
  }

  // gated attention pooling
  k_gemm<<<dim3(64, 4), 256, 0, stream>>>(buf1, aw, ab, qbuf, nullptr, 0);
  k_gemm<<<dim3(64, 4), 256, 0, stream>>>(buf1, bw, bb, kbuf, nullptr, 0);
  k_gate<<<kN, 256, 0, stream>>>(qbuf, kbuf, cw, cb, Abuf);
  k_softmax_red<<<1, 256, 0, stream>>>(Abuf, red);
  k_pool_part<<<64, 256, 0, stream>>>(Abuf, red, buf1, ppart);
  k_pool_fin<<<1, 256, 0, stream>>>(ppart, out_w, out_b, (float*)d_out);
}

// Round 4
// 341.316 us; speedup vs baseline: 1.4499x; 1.4499x over previous
//
#include <hip/hip_runtime.h>
#include <math.h>

constexpr int kN = 4096;
constexpr int kM = 4100;
constexpr int kD = 256;
constexpr int ROWCAP = 64;
constexpr int COLCAP = 64;
constexpr int EB_CHUNKS = 16;
constexpr float kLnEps = 1e-5f;
constexpr float kScale = 0.17677669529663687f; // 1/sqrt(32)

__device__ __forceinline__ float waveSum(float v) {
#pragma unroll
  for (int m = 32; m >= 1; m >>= 1) v += __shfl_xor(v, m);
  return v;
}
__device__ __forceinline__ float waveMax(float v) {
#pragma unroll
  for (int m = 32; m >= 1; m >>= 1) v = fmaxf(v, __shfl_xor(v, m));
  return v;
}
__device__ __forceinline__ float blockSum256(float v, float* sh) {
  v = waveSum(v);
  int lane = threadIdx.x & 63, w = threadIdx.x >> 6;
  __syncthreads();
  if (lane == 0) sh[w] = v;
  __syncthreads();
  return sh[0] + sh[1] + sh[2] + sh[3];
}

// ---------------- sparse build ----------------
// one wave per row; float4 loads; ballot prefix scan keeps ascending-m order.
// 16 chunks x (64 lanes x float4 = 256 cols) = 4096 columns.  (R2 bug: stride
// was 1024 with only 4 chunks -> 75% of columns never scanned.)
__global__ __launch_bounds__(256) void k_build_csr(
    const float* __restrict__ H, int* __restrict__ row_cnt, int* __restrict__ row_idx,
    int* __restrict__ col_cnt, int* __restrict__ col_idx, float* __restrict__ col_val) {
  int n = (blockIdx.x * blockDim.x + threadIdx.x) >> 6;
  int lane = threadIdx.x & 63;
  const float* hrow = H + (size_t)n * kM;
  unsigned long long below = (1ull << lane) - 1ull;
  int cnt = 0;
#pragma unroll
  for (int c = 0; c < 16; ++c) {
    int mbase = c * 256 + lane * 4;
    float4 v4 = *(const float4*)&hrow[mbase];
    float vv[4] = {v4.x, v4.y, v4.z, v4.w};
    unsigned long long bal[4];
#pragma unroll
    for (int j = 0; j < 4; ++j) bal[j] = __ballot(vv[j] != 0.0f);
    int pre = 0, tot = 0;
#pragma unroll
    for (int j = 0; j < 4; ++j) { pre += __popcll(bal[j] & below); tot += __popcll(bal[j]); }
    int local = 0;
#pragma unroll
    for (int j = 0; j < 4; ++j) {
      if (vv[j] != 0.0f) {
        int m = mbase + j;
        int pos = cnt + pre + local;
        if (pos < ROWCAP) row_idx[n * ROWCAP + pos] = m;
        int pc = atomicAdd(&col_cnt[m], 1);
        if (pc < COLCAP) { col_idx[m * COLCAP + pc] = n; col_val[m * COLCAP + pc] = vv[j]; }
        local++;
      }
    }
    cnt += tot;
  }
  // tail m = 4096..4099
  float tv = (lane < 4) ? hrow[4096 + lane] : 0.0f;
  unsigned long long bal = __ballot(tv != 0.0f);
  if (tv != 0.0f) {
    int pos = cnt + __popcll(bal & below);
    if (pos < ROWCAP) row_idx[n * ROWCAP + pos] = 4096 + lane;
  }
  cnt += __popcll(bal);
  if (lane == 0) row_cnt[n] = cnt < ROWCAP ? cnt : ROWCAP;
}

// one wave per column: sort CSC list by row index -> deterministic order.
__global__ __launch_bounds__(256) void k_sort_csc(
    int* __restrict__ col_cnt, int* __restrict__ col_idx, float* __restrict__ col_val,
    float* __restrict__ deg) {
  int c = (blockIdx.x * blockDim.x + threadIdx.x) >> 6;
  int lane = threadIdx.x & 63;
  if (c < 4 && lane == 0) deg[kN + c] = 0.0f;  // zero deg tail (accumulated later)
  int cnt = col_cnt[c]; if (cnt > COLCAP) cnt = COLCAP;
  int iv = 0x7fffffff; float vv = 0.0f;
  if (lane < cnt) { iv = col_idx[c * COLCAP + lane]; vv = col_val[c * COLCAP + lane]; }
  float dsum = waveSum(vv);
  int rank = 0;
  for (int j = 0; j < 64; ++j) {
    int ivj = __shfl(iv, j);
    if (ivj < iv) rank++;
  }
  if (lane < cnt) { col_idx[c * COLCAP + rank] = iv; col_val[c * COLCAP + rank] = vv; }
  if (lane == 0) { deg[c] = dsum; col_cnt[c] = cnt; }
}

// ---------------- per-layer compute ----------------
// per-row LN stats (mean, rstd); one wave per row, float4
__global__ __launch_bounds__(256) void k_ln_stats(
    const float* __restrict__ X, float* __restrict__ stats) {
  int row = blockIdx.x * 4 + (threadIdx.x >> 6);
  int lane = threadIdx.x & 63;
  float4 v = *(const float4*)&X[(size_t)row * kD + lane * 4];
  float s = waveSum(v.x + v.y + v.z + v.w);
  float mean = s * (1.0f / kD);
  float dx = v.x - mean, dy = v.y - mean, dz = v.z - mean, dw = v.w - mean;
  float q = waveSum(dx * dx + dy * dy + dz * dz + dw * dw);
  float rstd = rsqrtf(q * (1.0f / kD) + kLnEps);
  if (lane == 0) { stats[row * 2] = mean; stats[row * 2 + 1] = rstd; }
}

// E rows (m < kN) from sorted CSC, LN fused; one wave per edge, float4 gather
__global__ __launch_bounds__(256) void k_e_small(
    const float* __restrict__ X, const int* __restrict__ col_cnt,
    const int* __restrict__ col_idx, const float* __restrict__ col_val,
    const float* __restrict__ deg, const float* __restrict__ g,
    const float* __restrict__ b, float* __restrict__ En) {
  __shared__ int sidx[4][COLCAP];
  __shared__ float sval[4][COLCAP];
  int wq = threadIdx.x >> 6, lane = threadIdx.x & 63;
  int m = blockIdx.x * 4 + wq;
  int cnt = col_cnt[m];
  if (lane < cnt) { sidx[wq][lane] = col_idx[m * COLCAP + lane]; sval[wq][lane] = col_val[m * COLCAP + lane]; }
  __syncthreads();
  float ax = 0.f, ay = 0.f, az = 0.f, aw4 = 0.f;
  for (int e = 0; e < cnt; ++e) {
    float vv = sval[wq][e];
    float4 xr = *(const float4*)&X[(size_t)sidx[wq][e] * kD + lane * 4];
    ax += vv * xr.x; ay += vv * xr.y; az += vv * xr.z; aw4 += vv * xr.w;
  }
  float inv = 1.0f / deg[m];
  ax *= inv; ay *= inv; az *= inv; aw4 *= inv;
  float mean = waveSum(ax + ay + az + aw4) * (1.0f / kD);
  float dx = ax - mean, dy = ay - mean, dz = az - mean, dw = aw4 - mean;
  float var = waveSum(dx * dx + dy * dy + dz * dz + dw * dw) * (1.0f / kD);
  float rstd = rsqrtf(var + kLnEps);
  float4 gv = *(const float4*)&g[lane * 4];
  float4 bv = *(const float4*)&b[lane * 4];
  float4 o;
  o.x = dx * rstd * gv.x + bv.x; o.y = dy * rstd * gv.y + bv.y;
  o.z = dz * rstd * gv.z + bv.z; o.w = dw * rstd * gv.w + bv.w;
  *(float4*)&En[(size_t)m * kD + lane * 4] = o;
}

// big (topo/stroma) columns: partial sums over 256-row slabs, reading H tail directly
__global__ __launch_bounds__(256) void k_e_big_part(
    const float* __restrict__ X, const float* __restrict__ H,
    float* __restrict__ part, float* __restrict__ deg, int add_deg) {
  __shared__ float hv[256];
  __shared__ float shr[4];
  int c = blockIdx.y, chunk = blockIdx.x, t = threadIdx.x;
  int r0 = chunk * 256;
  float v = H[(size_t)(r0 + t) * kM + kN + c];
  hv[t] = v;
  if (add_deg) {
    float ds = blockSum256(v, shr);   // values in {0,1}: integer-exact
    if (t == 0 && ds != 0.0f) atomicAdd(&deg[kN + c], ds);
  }
  __syncthreads();
  float s = 0.0f;
  for (int i = 0; i < 256; ++i) {
    float h = hv[i];
    if (h != 0.0f) s += h * X[(size_t)(r0 + i) * kD + t];
  }
  part[(size_t)(c * EB_CHUNKS + chunk) * kD + t] = s;
}

__global__ __launch_bounds__(256) void k_e_big_fin(
    const float* __restrict__ part, const float* __restrict__ deg,
    const float* __restrict__ g, const float* __restrict__ b, float* __restrict__ En) {
  __shared__ float sh[4];
  int c = blockIdx.x, d = threadIdx.x;
  float s = 0.0f;
#pragma unroll
  for (int k = 0; k < EB_CHUNKS; ++k) s += part[(size_t)(c * EB_CHUNKS + k) * kD + d];
  s *= (1.0f / deg[kN + c]);
  float mean = blockSum256(s, sh) * (1.0f / kD);
  float dv = s - mean;
  float var = blockSum256(dv * dv, sh) * (1.0f / kD);
  En[(size_t)(kN + c) * kD + d] = dv * rsqrtf(var + kLnEps) * g[d] + b[d];
}

// ---------------- GEMM (batched via blockIdx.z) ----------------
// mode 0: C = A@W^T + bias
// mode 1: C = 0.5*relu(A@W^T + bias) + 0.5*blend
// mode 2: C = LN(A)@W^T + bias  (stats = per-row [mean,rstd]; g/b = LN affine)
struct GArg {
  const float* A; const float* W; const float* bias; float* C;
  const float* blend; const float* stats; const float* g; const float* b;
  int mode;
};

__global__ __launch_bounds__(256) void k_gemm2(GArg a0, GArg a1) {
  GArg ga = blockIdx.z ? a1 : a0;
  __shared__ __align__(16) float sA[32][68];
  __shared__ __align__(16) float sW[32][68];
  int t = threadIdx.x;
  int tx = t & 15, ty = t >> 4;
  int row0 = blockIdx.x * 64, col0 = blockIdx.y * 64;
  int kl = t & 31, nb = t >> 5;
  float sm_[8], sr_[8];
  if (ga.mode == 2) {
#pragma unroll
    for (int i = 0; i < 8; ++i) {
      int row = row0 + i * 8 + nb;
      sm_[i] = ga.stats[row * 2];
      sr_[i] = ga.stats[row * 2 + 1];
    }
  }
  float acc[4][4] = {};
  for (int k0 = 0; k0 < kD; k0 += 32) {
    float gk = 0.f, bk = 0.f;
    if (ga.mode == 2) { gk = ga.g[k0 + kl]; bk = ga.b[k0 + kl]; }
#pragma unroll
    for (int i = 0; i < 8; ++i) {
      int nl = i * 8 + nb;
      float v = ga.A[(size_t)(row0 + nl) * kD + k0 + kl];
      if (ga.mode == 2) v = (v - sm_[i]) * sr_[i] * gk + bk;
      sA[kl][nl] = v;
      sW[kl][nl] = ga.W[(size_t)(col0 + nl) * kD + k0 + kl];
    }
    __syncthreads();
#pragma unroll
    for (int kk = 0; kk < 32; ++kk) {
      float4 av = *(const float4*)&sA[kk][ty * 4];
      float4 wv = *(const float4*)&sW[kk][tx * 4];
      acc[0][0] += av.x * wv.x; acc[0][1] += av.x * wv.y; acc[0][2] += av.x * wv.z; acc[0][3] += av.x * wv.w;
      acc[1][0] += av.y * wv.x; acc[1][1] += av.y * wv.y; acc[1][2] += av.y * wv.z; acc[1][3] += av.y * wv.w;
      acc[2][0] += av.z * wv.x; acc[2][1] += av.z * wv.y; acc[2][2] += av.z * wv.z; acc[2][3] += av.z * wv.w;
      acc[3][0] += av.w * wv.x; acc[3][1] += av.w * wv.y; acc[3][2] += av.w * wv.z; acc[3][3] += av.w * wv.w;
    }
    __syncthreads();
  }
  int cb = col0 + tx * 4;
  float4 bv = *(const float4*)&ga.bias[cb];
#pragma unroll
  for (int i = 0; i < 4; ++i) {
    int r = row0 + ty * 4 + i;
    float4 v;
    v.x = acc[i][0] + bv.x; v.y = acc[i][1] + bv.y;
    v.z = acc[i][2] + bv.z; v.w = acc[i][3] + bv.w;
    if (ga.mode == 1) {
      float4 x0 = *(const float4*)&ga.blend[(size_t)r * kD + cb];
      v.x = 0.5f * fmaxf(v.x, 0.0f) + 0.5f * x0.x;
      v.y = 0.5f * fmaxf(v.y, 0.0f) + 0.5f * x0.y;
      v.z = 0.5f * fmaxf(v.z, 0.0f) + 0.5f * x0.z;
      v.w = 0.5f * fmaxf(v.w, 0.0f) + 0.5f * x0.w;
    }
    *(float4*)&ga.C[(size_t)r * kD + cb] = v;
  }
}

// last 4 k-rows (3x Wkt, 1x Wks), float4 streams
__global__ __launch_bounds__(256) void k_ktail(
    const float* __restrict__ En, const float* __restrict__ Wkt_w,
    const float* __restrict__ Wkt_b, const float* __restrict__ Wks_w,
    const float* __restrict__ Wks_b, float* __restrict__ K) {
  __shared__ float er[4][kD];
  int t = threadIdx.x;
  for (int i = t; i < 4 * kD; i += 256)
    er[i >> 8][i & 255] = En[(size_t)(kN + (i >> 8)) * kD + (i & 255)];
  __syncthreads();
  float a0 = 0.f, a1 = 0.f, a2 = 0.f, a3 = 0.f;
  for (int k = 0; k < kD; k += 4) {
    float4 wt = *(const float4*)&Wkt_w[(size_t)t * kD + k];
    float4 ws = *(const float4*)&Wks_w[(size_t)t * kD + k];
    float4 e0 = *(const float4*)&er[0][k];
    float4 e1 = *(const float4*)&er[1][k];
    float4 e2 = *(const float4*)&er[2][k];
    float4 e3 = *(const float4*)&er[3][k];
    a0 += e0.x * wt.x + e0.y * wt.y + e0.z * wt.z + e0.w * wt.w;
    a1 += e1.x * wt.x + e1.y * wt.y + e1.z * wt.z + e1.w * wt.w;
    a2 += e2.x * wt.x + e2.y * wt.y + e2.z * wt.z + e2.w * wt.w;
    a3 += e3.x * ws.x + e3.y * ws.y + e3.z * ws.z + e3.w * ws.w;
  }
  float bt = Wkt_b[t];
  K[(size_t)(kN + 0) * kD + t] = a0 + bt;
  K[(size_t)(kN + 1) * kD + t] = a1 + bt;
  K[(size_t)(kN + 2) * kD + t] = a2 + bt;
  K[(size_t)(kN + 3) * kD + t] = a3 + Wks_b[t];
}

// sparse masked attention, single-pass online softmax.
// block per row n; thread = (head h = t>>5, dim dd = t&31)
__global__ __launch_bounds__(256) void k_attn(
    const float* __restrict__ q, const float* __restrict__ kbuf,
    const int* __restrict__ row_cnt, const int* __restrict__ row_idx,
    float* __restrict__ featA) {
  __shared__ int sm[ROWCAP];
  int n = blockIdx.x, t = threadIdx.x;
  int cnt = row_cnt[n];
  if (t < cnt) sm[t] = row_idx[n * ROWCAP + t];
  __syncthreads();
  float qv = q[(size_t)n * kD + t];
  float m = -3.4e38f, l = 0.0f, acc = 0.0f;
  for (int e = 0; e < cnt; ++e) {
    float kv = kbuf[(size_t)sm[e] * kD + t];
    float s = qv * kv;
#pragma unroll
    for (int mm = 16; mm >= 1; mm >>= 1) s += __shfl_xor(s, mm);
    s *= kScale;
    float mn = fmaxf(m, s);
    float sc = __expf(m - mn);
    float p = __expf(s - mn);
    acc = acc * sc + p * kv;
    l = l * sc + p;
    m = mn;
  }
  featA[(size_t)n * kD + t] = acc / l;
}

// ---------------- pooling head ----------------
__global__ __launch_bounds__(256) void k_gate(
    const float* __restrict__ araw, const float* __restrict__ braw,
    const float* __restrict__ cw, const float* __restrict__ cb,
    float* __restrict__ Abuf) {
  __shared__ float sh[4];
  int n = blockIdx.x, o = threadIdx.x;
  float a = tanhf(araw[(size_t)n * kD + o]);
  float b = 1.0f / (1.0f + expf(-braw[(size_t)n * kD + o]));
  float s = blockSum256(a * b * cw[o], sh);
  if (o == 0) Abuf[n] = s + cb[0];
}

__global__ __launch_bounds__(256) void k_softmax_red(
    const float* __restrict__ Abuf, float* __restrict__ red) {
  __shared__ float sh[4];
  int t = threadIdx.x;
  float mx = -3.4e38f;
  for (int i = t; i < kN; i += 256) mx = fmaxf(mx, Abuf[i]);
  mx = waveMax(mx);
  int lane = t & 63, w = t >> 6;
  if (lane == 0) sh[w] = mx;
  __syncthreads();
  mx = fmaxf(fmaxf(sh[0], sh[1]), fmaxf(sh[2], sh[3]));
  __syncthreads();
  float s = 0.0f;
  for (int i = t; i < kN; i += 256) s += expf(Abuf[i] - mx);
  s = blockSum256(s, sh);
  if (t == 0) { red[0] = mx; red[1] = 1.0f / s; }
}

__global__ __launch_bounds__(256) void k_pool_part(
    const float* __restrict__ Abuf, const float* __restrict__ red,
    const float* __restrict__ feat, float* __restrict__ part) {
  int b = blockIdx.x, d = threadIdx.x;
  float mx = red[0], inv = red[1];
  float acc = 0.0f;
  for (int r = 0; r < 64; ++r) {
    int n = b * 64 + r;
    float p = expf(Abuf[n] - mx) * inv;
    acc += p * feat[(size_t)n * kD + d];
  }
  part[(size_t)b * kD + d] = acc;
}

__global__ __launch_bounds__(256) void k_pool_fin(
    const float* __restrict__ part, const float* __restrict__ out_w,
    const float* __restrict__ out_b, float* __restrict__ out) {
  __shared__ float pooled[kD];
  int d = threadIdx.x;
  float s = 0.0f;
#pragma unroll
  for (int b = 0; b < 64; ++b) s += part[(size_t)b * kD + d];
  pooled[d] = s;
  __syncthreads();
  if (d < 4) {
    float o = out_b[d];
    for (int i = 0; i < kD; ++i) o += pooled[i] * out_w[(size_t)d * kD + i];
    out[d] = o;
  }
}

extern "C" void kernel_launch(void* const* d_in, const int* in_sizes, int n_in,
                              void* d_out, int out_size, void* d_ws, size_t ws_size,
                              hipStream_t stream) {
  (void)in_sizes; (void)n_in; (void)out_size; (void)ws_size;
  const float* X     = (const float*)d_in[0];
  const float* H     = (const float*)d_in[1];
  const float* Wq_w  = (const float*)d_in[2];
  const float* Wq_b  = (const float*)d_in[3];
  const float* Wkn_w = (const float*)d_in[4];
  const float* Wkn_b = (const float*)d_in[5];
  const float* Wkt_w = (const float*)d_in[6];
  const float* Wkt_b = (const float*)d_in[7];
  const float* Wks_w = (const float*)d_in[8];
  const float* Wks_b = (const float*)d_in[9];
  const float* fc_w  = (const float*)d_in[10];
  const float* fc_b  = (const float*)d_in[11];
  const float* ln_g  = (const float*)d_in[12];
  const float* ln_b  = (const float*)d_in[13];
  const float* aw    = (const float*)d_in[14];
  const float* ab    = (const float*)d_in[15];
  const float* bw    = (const float*)d_in[16];
  const float* bb    = (const float*)d_in[17];
  const float* cw    = (const float*)d_in[18];
  const float* cb    = (const float*)d_in[19];
  const float* out_w = (const float*)d_in[20];
  const float* out_b = (const float*)d_in[21];

  char* p = (char*)d_ws;
  auto alloc = [&](size_t bytes) -> void* {
    void* r = (void*)p;
    p += (bytes + 255) & ~(size_t)255;
    return r;
  };
  int*   row_cnt = (int*)alloc(kN * 4);
  int*   row_idx = (int*)alloc((size_t)kN * ROWCAP * 4);
  int*   col_cnt = (int*)alloc(kN * 4);
  int*   col_idx = (int*)alloc((size_t)kN * COLCAP * 4);
  float* col_val = (float*)alloc((size_t)kN * COLCAP * 4);
  float* deg     = (float*)alloc(kM * 4);
  float* stats   = (float*)alloc((size_t)kN * 2 * 4);
  float* En      = (float*)alloc((size_t)kM * kD * 4);
  float* qbuf    = (float*)alloc((size_t)kN * kD * 4);
  float* kbuf    = (float*)alloc((size_t)kM * kD * 4);
  float* featA   = (float*)alloc((size_t)kN * kD * 4);
  float* buf0    = (float*)alloc((size_t)kN * kD * 4);
  float* buf1    = (float*)alloc((size_t)kN * kD * 4);
  float* ebpart  = (float*)alloc((size_t)4 * EB_CHUNKS * kD * 4);
  float* Abuf    = (float*)alloc(kN * 4);
  float* red     = (float*)alloc(2 * 4);
  float* ppart   = (float*)alloc(64 * kD * 4);

  hipMemsetAsync(col_cnt, 0, kN * 4, stream);
  k_build_csr<<<kN / 4, 256, 0, stream>>>(H, row_cnt, row_idx, col_cnt, col_idx, col_val);
  k_sort_csc<<<kN / 4, 256, 0, stream>>>(col_cnt, col_idx, col_val, deg);

  GArg dummy = {};
  for (int layer = 0; layer < 2; ++layer) {
    const float* Xc = layer ? buf0 : X;
    float* Xout = layer ? buf1 : buf0;
    size_t wo = (size_t)layer * kD * kD;
    size_t bo = (size_t)layer * kD;
    k_ln_stats<<<kN / 4, 256, 0, stream>>>(Xc, stats);
    k_e_small<<<kN / 4, 256, 0, stream>>>(Xc, col_cnt, col_idx, col_val, deg,
                                          ln_g + bo, ln_b + bo, En);
    k_e_big_part<<<dim3(EB_CHUNKS, 4), 256, 0, stream>>>(Xc, H, ebpart, deg, layer == 0);
    k_e_big_fin<<<4, 256, 0, stream>>>(ebpart, deg, ln_g + bo, ln_b + bo, En);
    GArg qa = {Xc, Wq_w + wo, Wq_b + bo, qbuf, nullptr, stats, ln_g + bo, ln_b + bo, 2};
    GArg ka = {En, Wkn_w + wo, Wkn_b + bo, kbuf, nullptr, nullptr, nullptr, nullptr, 0};
    k_gemm2<<<dim3(64, 4, 2), 256, 0, stream>>>(qa, ka);
    k_ktail<<<1, 256, 0, stream>>>(En, Wkt_w + wo, Wkt_b + bo, Wks_w + wo, Wks_b + bo, kbuf);
    k_attn<<<kN, 256, 0, stream>>>(qbuf, kbuf, row_cnt, row_idx, featA);
    GArg fa = {featA, fc_w + wo, fc_b + bo, Xout, Xc, nullptr, nullptr, nullptr, 1};
    k_gemm2<<<dim3(64, 4, 1), 256, 0, stream>>>(fa, dummy);
  }

  GArg aa = {buf1, aw, ab, qbuf, nullptr, nullptr, nullptr, nullptr, 0};
  GArg ba = {buf1, bw, bb, kbuf, nullptr, nullptr, nullptr, nullptr, 0};
  k_gemm2<<<dim3(64, 4, 2), 256, 0, stream>>>(aa, ba);
  k_gate<<<kN, 256, 0, stream>>>(qbuf, kbuf, cw, cb, Abuf);
  k_softmax_red<<<1, 256, 0, stream>>>(Abuf, red);
  k_pool_part<<<64, 256, 0, stream>>>(Abuf, red, buf1, ppart);
  k_pool_fin<<<1, 256, 0, stream>>>(ppart, out_w, out_b, (float*)d_out);
}

// Round 5
// 330.445 us; speedup vs baseline: 1.4976x; 1.0329x over previous
//
#include <hip/hip_runtime.h>
#include <math.h>

constexpr int kN = 4096;
constexpr int kM = 4100;
constexpr int kD = 256;
constexpr int ROWCAP = 64;
constexpr int COLCAP = 64;
constexpr int EB_CHUNKS = 16;
constexpr float kLnEps = 1e-5f;
constexpr float kScale = 0.17677669529663687f; // 1/sqrt(32)

__device__ __forceinline__ float waveSum(float v) {
#pragma unroll
  for (int m = 32; m >= 1; m >>= 1) v += __shfl_xor(v, m);
  return v;
}
__device__ __forceinline__ float waveMax(float v) {
#pragma unroll
  for (int m = 32; m >= 1; m >>= 1) v = fmaxf(v, __shfl_xor(v, m));
  return v;
}
__device__ __forceinline__ float blockSum256(float v, float* sh) {
  v = waveSum(v);
  int lane = threadIdx.x & 63, w = threadIdx.x >> 6;
  __syncthreads();
  if (lane == 0) sh[w] = v;
  __syncthreads();
  return sh[0] + sh[1] + sh[2] + sh[3];
}

// ---------------- sparse build ----------------
// one wave per row. ALL 16 float4 chunk-loads prefetched into registers first
// (R4: VGPR=12 showed serialized loads -> 1 TB/s latency-bound), then the
// ballot prefix-scan compaction. Ascending-m order preserved.
__global__ __launch_bounds__(256) void k_build_csr(
    const float* __restrict__ H, int* __restrict__ row_cnt, int* __restrict__ row_idx,
    int* __restrict__ col_cnt, int* __restrict__ col_idx, float* __restrict__ col_val) {
  int n = (blockIdx.x * blockDim.x + threadIdx.x) >> 6;
  int lane = threadIdx.x & 63;
  const float* hrow = H + (size_t)n * kM;
  float4 v[16];
#pragma unroll
  for (int c = 0; c < 16; ++c) v[c] = *(const float4*)&hrow[c * 256 + lane * 4];
  float tv = (lane < 4) ? hrow[4096 + lane] : 0.0f;
  unsigned long long below = (1ull << lane) - 1ull;
  int cnt = 0;
#pragma unroll
  for (int c = 0; c < 16; ++c) {
    int mbase = c * 256 + lane * 4;
    float vv[4] = {v[c].x, v[c].y, v[c].z, v[c].w};
    unsigned long long bal[4];
#pragma unroll
    for (int j = 0; j < 4; ++j) bal[j] = __ballot(vv[j] != 0.0f);
    int pre = 0, tot = 0;
#pragma unroll
    for (int j = 0; j < 4; ++j) { pre += __popcll(bal[j] & below); tot += __popcll(bal[j]); }
    int local = 0;
#pragma unroll
    for (int j = 0; j < 4; ++j) {
      if (vv[j] != 0.0f) {
        int m = mbase + j;
        int pos = cnt + pre + local;
        if (pos < ROWCAP) row_idx[n * ROWCAP + pos] = m;
        int pc = atomicAdd(&col_cnt[m], 1);
        if (pc < COLCAP) { col_idx[m * COLCAP + pc] = n; col_val[m * COLCAP + pc] = vv[j]; }
        local++;
      }
    }
    cnt += tot;
  }
  // tail m = 4096..4099
  unsigned long long bal = __ballot(tv != 0.0f);
  if (tv != 0.0f) {
    int pos = cnt + __popcll(bal & below);
    if (pos < ROWCAP) row_idx[n * ROWCAP + pos] = 4096 + lane;
  }
  cnt += __popcll(bal);
  if (lane == 0) row_cnt[n] = cnt < ROWCAP ? cnt : ROWCAP;
}

// one wave per column: sort CSC list by row index -> deterministic order.
__global__ __launch_bounds__(256) void k_sort_csc(
    int* __restrict__ col_cnt, int* __restrict__ col_idx, float* __restrict__ col_val,
    float* __restrict__ deg) {
  int c = (blockIdx.x * blockDim.x + threadIdx.x) >> 6;
  int lane = threadIdx.x & 63;
  if (c < 4 && lane == 0) deg[kN + c] = 0.0f;  // zero deg tail (accumulated in k_pre L0)
  int cnt = col_cnt[c]; if (cnt > COLCAP) cnt = COLCAP;
  int iv = 0x7fffffff; float vv = 0.0f;
  if (lane < cnt) { iv = col_idx[c * COLCAP + lane]; vv = col_val[c * COLCAP + lane]; }
  float dsum = waveSum(vv);
  int rank = 0;
  for (int j = 0; j < 64; ++j) {
    int ivj = __shfl(iv, j);
    if (ivj < iv) rank++;
  }
  if (lane < cnt) { col_idx[c * COLCAP + rank] = iv; col_val[c * COLCAP + rank] = vv; }
  if (lane == 0) { deg[c] = dsum; col_cnt[c] = cnt; }
}

// ---------------- fused per-layer pre-pass ----------------
// blocks [0,1024): E rows (sparse CSC gather + LN) -> En
// blocks [1024,2048): per-row LN stats of X -> stats
// blocks [2048,2112): big-column (topo/stroma) partial sums -> ebpart (+deg L0)
__global__ __launch_bounds__(256) void k_pre(
    const float* __restrict__ X, const float* __restrict__ H,
    const int* __restrict__ col_cnt, const int* __restrict__ col_idx,
    const float* __restrict__ col_val, float* __restrict__ deg,
    const float* __restrict__ g, const float* __restrict__ b,
    float* __restrict__ stats, float* __restrict__ En,
    float* __restrict__ ebpart, int add_deg) {
  __shared__ int sidx[4][COLCAP];
  __shared__ float sval[4][COLCAP];
  __shared__ float shr[4];
  int bid = blockIdx.x, t = threadIdx.x;
  int wq = t >> 6, lane = t & 63;
  if (bid < 1024) {
    // ---- E rows + LN ----
    int m = bid * 4 + wq;
    int cnt = col_cnt[m];
    if (lane < cnt) { sidx[wq][lane] = col_idx[m * COLCAP + lane]; sval[wq][lane] = col_val[m * COLCAP + lane]; }
    __syncthreads();
    float ax = 0.f, ay = 0.f, az = 0.f, aw4 = 0.f;
    for (int e = 0; e < cnt; ++e) {
      float vv = sval[wq][e];
      float4 xr = *(const float4*)&X[(size_t)sidx[wq][e] * kD + lane * 4];
      ax += vv * xr.x; ay += vv * xr.y; az += vv * xr.z; aw4 += vv * xr.w;
    }
    float inv = 1.0f / deg[m];
    ax *= inv; ay *= inv; az *= inv; aw4 *= inv;
    float mean = waveSum(ax + ay + az + aw4) * (1.0f / kD);
    float dx = ax - mean, dy = ay - mean, dz = az - mean, dw = aw4 - mean;
    float var = waveSum(dx * dx + dy * dy + dz * dz + dw * dw) * (1.0f / kD);
    float rstd = rsqrtf(var + kLnEps);
    float4 gv = *(const float4*)&g[lane * 4];
    float4 bv = *(const float4*)&b[lane * 4];
    float4 o;
    o.x = dx * rstd * gv.x + bv.x; o.y = dy * rstd * gv.y + bv.y;
    o.z = dz * rstd * gv.z + bv.z; o.w = dw * rstd * gv.w + bv.w;
    *(float4*)&En[(size_t)m * kD + lane * 4] = o;
  } else if (bid < 2048) {
    // ---- LN stats of X ----
    int row = (bid - 1024) * 4 + wq;
    float4 v = *(const float4*)&X[(size_t)row * kD + lane * 4];
    float s = waveSum(v.x + v.y + v.z + v.w);
    float mean = s * (1.0f / kD);
    float dx = v.x - mean, dy = v.y - mean, dz = v.z - mean, dw = v.w - mean;
    float q = waveSum(dx * dx + dy * dy + dz * dz + dw * dw);
    float rstd = rsqrtf(q * (1.0f / kD) + kLnEps);
    if (lane == 0) { stats[row * 2] = mean; stats[row * 2 + 1] = rstd; }
  } else {
    // ---- big columns partial sums ----
    __shared__ float hv[256];
    int idx = bid - 2048;
    int chunk = idx & 15, c = idx >> 4;
    int r0 = chunk * 256;
    float v = H[(size_t)(r0 + t) * kM + kN + c];
    hv[t] = v;
    if (add_deg) {
      float ds = blockSum256(v, shr);   // values in {0,1}: integer-exact
      if (t == 0 && ds != 0.0f) atomicAdd(&deg[kN + c], ds);
    }
    __syncthreads();
    float s = 0.0f;
    for (int i = 0; i < 256; ++i) {
      float h = hv[i];
      if (h != 0.0f) s += h * X[(size_t)(r0 + i) * kD + t];
    }
    ebpart[(size_t)(c * EB_CHUNKS + chunk) * kD + t] = s;
  }
}

// single block: finalize the 4 big-edge rows (LN, kept in LDS) then the
// Wkt/Wks projections into kbuf tail.  En tail never touches global memory.
__global__ __launch_bounds__(256) void k_finktail(
    const float* __restrict__ part, const float* __restrict__ deg,
    const float* __restrict__ g, const float* __restrict__ b,
    const float* __restrict__ Wkt_w, const float* __restrict__ Wkt_b,
    const float* __restrict__ Wks_w, const float* __restrict__ Wks_b,
    float* __restrict__ K) {
  __shared__ float er[4][kD];
  __shared__ float sh[4];
  int t = threadIdx.x;
  for (int c = 0; c < 4; ++c) {
    float s = 0.0f;
#pragma unroll
    for (int k = 0; k < EB_CHUNKS; ++k) s += part[(size_t)(c * EB_CHUNKS + k) * kD + t];
    s *= (1.0f / deg[kN + c]);
    float mean = blockSum256(s, sh) * (1.0f / kD);
    float dv = s - mean;
    float var = blockSum256(dv * dv, sh) * (1.0f / kD);
    er[c][t] = dv * rsqrtf(var + kLnEps) * g[t] + b[t];
  }
  __syncthreads();
  float a0 = 0.f, a1 = 0.f, a2 = 0.f, a3 = 0.f;
  for (int k = 0; k < kD; k += 4) {
    float4 wt = *(const float4*)&Wkt_w[(size_t)t * kD + k];
    float4 ws = *(const float4*)&Wks_w[(size_t)t * kD + k];
    float4 e0 = *(const float4*)&er[0][k];
    float4 e1 = *(const float4*)&er[1][k];
    float4 e2 = *(const float4*)&er[2][k];
    float4 e3 = *(const float4*)&er[3][k];
    a0 += e0.x * wt.x + e0.y * wt.y + e0.z * wt.z + e0.w * wt.w;
    a1 += e1.x * wt.x + e1.y * wt.y + e1.z * wt.z + e1.w * wt.w;
    a2 += e2.x * wt.x + e2.y * wt.y + e2.z * wt.z + e2.w * wt.w;
    a3 += e3.x * ws.x + e3.y * ws.y + e3.z * ws.z + e3.w * ws.w;
  }
  float bt = Wkt_b[t];
  K[(size_t)(kN + 0) * kD + t] = a0 + bt;
  K[(size_t)(kN + 1) * kD + t] = a1 + bt;
  K[(size_t)(kN + 2) * kD + t] = a2 + bt;
  K[(size_t)(kN + 3) * kD + t] = a3 + Wks_b[t];
}

// ---------------- GEMM (batched via blockIdx.z) ----------------
// mode 0: C = A@W^T + bias
// mode 1: C = 0.5*relu(A@W^T + bias) + 0.5*blend
// mode 2: C = LN(A)@W^T + bias  (stats = per-row [mean,rstd]; g/b = LN affine)
struct GArg {
  const float* A; const float* W; const float* bias; float* C;
  const float* blend; const float* stats; const float* g; const float* b;
  int mode;
};

__global__ __launch_bounds__(256) void k_gemm2(GArg a0, GArg a1) {
  GArg ga = blockIdx.z ? a1 : a0;
  __shared__ __align__(16) float sA[32][68];
  __shared__ __align__(16) float sW[32][68];
  int t = threadIdx.x;
  int tx = t & 15, ty = t >> 4;
  int row0 = blockIdx.x * 64, col0 = blockIdx.y * 64;
  int kl = t & 31, nb = t >> 5;
  float sm_[8], sr_[8];
  if (ga.mode == 2) {
#pragma unroll
    for (int i = 0; i < 8; ++i) {
      int row = row0 + i * 8 + nb;
      sm_[i] = ga.stats[row * 2];
      sr_[i] = ga.stats[row * 2 + 1];
    }
  }
  float acc[4][4] = {};
  for (int k0 = 0; k0 < kD; k0 += 32) {
    float gk = 0.f, bk = 0.f;
    if (ga.mode == 2) { gk = ga.g[k0 + kl]; bk = ga.b[k0 + kl]; }
#pragma unroll
    for (int i = 0; i < 8; ++i) {
      int nl = i * 8 + nb;
      float v = ga.A[(size_t)(row0 + nl) * kD + k0 + kl];
      if (ga.mode == 2) v = (v - sm_[i]) * sr_[i] * gk + bk;
      sA[kl][nl] = v;
      sW[kl][nl] = ga.W[(size_t)(col0 + nl) * kD + k0 + kl];
    }
    __syncthreads();
#pragma unroll
    for (int kk = 0; kk < 32; ++kk) {
      float4 av = *(const float4*)&sA[kk][ty * 4];
      float4 wv = *(const float4*)&sW[kk][tx * 4];
      acc[0][0] += av.x * wv.x; acc[0][1] += av.x * wv.y; acc[0][2] += av.x * wv.z; acc[0][3] += av.x * wv.w;
      acc[1][0] += av.y * wv.x; acc[1][1] += av.y * wv.y; acc[1][2] += av.y * wv.z; acc[1][3] += av.y * wv.w;
      acc[2][0] += av.z * wv.x; acc[2][1] += av.z * wv.y; acc[2][2] += av.z * wv.z; acc[2][3] += av.z * wv.w;
      acc[3][0] += av.w * wv.x; acc[3][1] += av.w * wv.y; acc[3][2] += av.w * wv.z; acc[3][3] += av.w * wv.w;
    }
    __syncthreads();
  }
  int cb = col0 + tx * 4;
  float4 bv = *(const float4*)&ga.bias[cb];
#pragma unroll
  for (int i = 0; i < 4; ++i) {
    int r = row0 + ty * 4 + i;
    float4 v;
    v.x = acc[i][0] + bv.x; v.y = acc[i][1] + bv.y;
    v.z = acc[i][2] + bv.z; v.w = acc[i][3] + bv.w;
    if (ga.mode == 1) {
      float4 x0 = *(const float4*)&ga.blend[(size_t)r * kD + cb];
      v.x = 0.5f * fmaxf(v.x, 0.0f) + 0.5f * x0.x;
      v.y = 0.5f * fmaxf(v.y, 0.0f) + 0.5f * x0.y;
      v.z = 0.5f * fmaxf(v.z, 0.0f) + 0.5f * x0.z;
      v.w = 0.5f * fmaxf(v.w, 0.0f) + 0.5f * x0.w;
    }
    *(float4*)&ga.C[(size_t)r * kD + cb] = v;
  }
}

// sparse masked attention, single-pass online softmax.
__global__ __launch_bounds__(256) void k_attn(
    const float* __restrict__ q, const float* __restrict__ kbuf,
    const int* __restrict__ row_cnt, const int* __restrict__ row_idx,
    float* __restrict__ featA) {
  __shared__ int sm[ROWCAP];
  int n = blockIdx.x, t = threadIdx.x;
  int cnt = row_cnt[n];
  if (t < cnt) sm[t] = row_idx[n * ROWCAP + t];
  __syncthreads();
  float qv = q[(size_t)n * kD + t];
  float m = -3.4e38f, l = 0.0f, acc = 0.0f;
  for (int e = 0; e < cnt; ++e) {
    float kv = kbuf[(size_t)sm[e] * kD + t];
    float s = qv * kv;
#pragma unroll
    for (int mm = 16; mm >= 1; mm >>= 1) s += __shfl_xor(s, mm);
    s *= kScale;
    float mn = fmaxf(m, s);
    float sc = __expf(m - mn);
    float p = __expf(s - mn);
    acc = acc * sc + p * kv;
    l = l * sc + p;
    m = mn;
  }
  featA[(size_t)n * kD + t] = acc / l;
}

// ---------------- pooling head ----------------
__global__ __launch_bounds__(256) void k_gate(
    const float* __restrict__ araw, const float* __restrict__ braw,
    const float* __restrict__ cw, const float* __restrict__ cb,
    float* __restrict__ Abuf) {
  __shared__ float sh[4];
  int n = blockIdx.x, o = threadIdx.x;
  float a = tanhf(araw[(size_t)n * kD + o]);
  float b = 1.0f / (1.0f + expf(-braw[(size_t)n * kD + o]));
  float s = blockSum256(a * b * cw[o], sh);
  if (o == 0) Abuf[n] = s + cb[0];
}

// 64 blocks; each redundantly computes the identical global max/sum over A
// (deterministic: same order in every block), then its 64-row partial pool.
__global__ __launch_bounds__(256) void k_pool_part(
    const float* __restrict__ Abuf, const float* __restrict__ feat,
    float* __restrict__ part) {
  __shared__ float sh[4];
  int b = blockIdx.x, t = threadIdx.x;
  float mx = -3.4e38f;
  for (int i = t; i < kN; i += 256) mx = fmaxf(mx, Abuf[i]);
  mx = waveMax(mx);
  int lane = t & 63, w = t >> 6;
  __syncthreads();
  if (lane == 0) sh[w] = mx;
  __syncthreads();
  mx = fmaxf(fmaxf(sh[0], sh[1]), fmaxf(sh[2], sh[3]));
  __syncthreads();
  float s = 0.0f;
  for (int i = t; i < kN; i += 256) s += expf(Abuf[i] - mx);
  s = blockSum256(s, sh);
  float inv = 1.0f / s;
  float acc = 0.0f;
  for (int r = 0; r < 64; ++r) {
    int n = b * 64 + r;
    float p = expf(Abuf[n] - mx) * inv;
    acc += p * feat[(size_t)n * kD + t];
  }
  part[(size_t)b * kD + t] = acc;
}

__global__ __launch_bounds__(256) void k_pool_fin(
    const float* __restrict__ part, const float* __restrict__ out_w,
    const float* __restrict__ out_b, float* __restrict__ out) {
  __shared__ float pooled[kD];
  int d = threadIdx.x;
  float s = 0.0f;
#pragma unroll
  for (int b = 0; b < 64; ++b) s += part[(size_t)b * kD + d];
  pooled[d] = s;
  __syncthreads();
  if (d < 4) {
    float o = out_b[d];
    for (int i = 0; i < kD; ++i) o += pooled[i] * out_w[(size_t)d * kD + i];
    out[d] = o;
  }
}

extern "C" void kernel_launch(void* const* d_in, const int* in_sizes, int n_in,
                              void* d_out, int out_size, void* d_ws, size_t ws_size,
                              hipStream_t stream) {
  (void)in_sizes; (void)n_in; (void)out_size; (void)ws_size;
  const float* X     = (const float*)d_in[0];
  const float* H     = (const float*)d_in[1];
  const float* Wq_w  = (const float*)d_in[2];
  const float* Wq_b  = (const float*)d_in[3];
  const float* Wkn_w = (const float*)d_in[4];
  const float* Wkn_b = (const float*)d_in[5];
  const float* Wkt_w = (const float*)d_in[6];
  const float* Wkt_b = (const float*)d_in[7];
  const float* Wks_w = (const float*)d_in[8];
  const float* Wks_b = (const float*)d_in[9];
  const float* fc_w  = (const float*)d_in[10];
  const float* fc_b  = (const float*)d_in[11];
  const float* ln_g  = (const float*)d_in[12];
  const float* ln_b  = (const float*)d_in[13];
  const float* aw    = (const float*)d_in[14];
  const float* ab    = (const float*)d_in[15];
  const float* bw    = (const float*)d_in[16];
  const float* bb    = (const float*)d_in[17];
  const float* cw    = (const float*)d_in[18];
  const float* cb    = (const float*)d_in[19];
  const float* out_w = (const float*)d_in[20];
  const float* out_b = (const float*)d_in[21];

  char* p = (char*)d_ws;
  auto alloc = [&](size_t bytes) -> void* {
    void* r = (void*)p;
    p += (bytes + 255) & ~(size_t)255;
    return r;
  };
  int*   row_cnt = (int*)alloc(kN * 4);
  int*   row_idx = (int*)alloc((size_t)kN * ROWCAP * 4);
  int*   col_cnt = (int*)alloc(kN * 4);
  int*   col_idx = (int*)alloc((size_t)kN * COLCAP * 4);
  float* col_val = (float*)alloc((size_t)kN * COLCAP * 4);
  float* deg     = (float*)alloc(kM * 4);
  float* stats   = (float*)alloc((size_t)kN * 2 * 4);
  float* En      = (float*)alloc((size_t)kM * kD * 4);
  float* qbuf    = (float*)alloc((size_t)kN * kD * 4);
  float* kbuf    = (float*)alloc((size_t)kM * kD * 4);
  float* featA   = (float*)alloc((size_t)kN * kD * 4);
  float* buf0    = (float*)alloc((size_t)kN * kD * 4);
  float* buf1    = (float*)alloc((size_t)kN * kD * 4);
  float* ebpart  = (float*)alloc((size_t)4 * EB_CHUNKS * kD * 4);
  float* Abuf    = (float*)alloc(kN * 4);
  float* ppart   = (float*)alloc(64 * kD * 4);

  hipMemsetAsync(col_cnt, 0, kN * 4, stream);
  k_build_csr<<<kN / 4, 256, 0, stream>>>(H, row_cnt, row_idx, col_cnt, col_idx, col_val);
  k_sort_csc<<<kN / 4, 256, 0, stream>>>(col_cnt, col_idx, col_val, deg);

  for (int layer = 0; layer < 2; ++layer) {
    const float* Xc = layer ? buf0 : X;
    float* Xout = layer ? buf1 : buf0;
    size_t wo = (size_t)layer * kD * kD;
    size_t bo = (size_t)layer * kD;
    k_pre<<<2112, 256, 0, stream>>>(Xc, H, col_cnt, col_idx, col_val, deg,
                                    ln_g + bo, ln_b + bo, stats, En, ebpart, layer == 0);
    GArg qa = {Xc, Wq_w + wo, Wq_b + bo, qbuf, nullptr, stats, ln_g + bo, ln_b + bo, 2};
    GArg ka = {En, Wkn_w + wo, Wkn_b + bo, kbuf, nullptr, nullptr, nullptr, nullptr, 0};
    k_gemm2<<<dim3(64, 4, 2), 256, 0, stream>>>(qa, ka);
    k_finktail<<<1, 256, 0, stream>>>(ebpart, deg, ln_g + bo, ln_b + bo,
                                      Wkt_w + wo, Wkt_b + bo, Wks_w + wo, Wks_b + bo, kbuf);
    k_attn<<<kN, 256, 0, stream>>>(qbuf, kbuf, row_cnt, row_idx, featA);
    GArg fa = {featA, fc_w + wo, fc_b + bo, Xout, Xc, nullptr, nullptr, nullptr, 1};
    GArg dummy = {};
    k_gemm2<<<dim3(64, 4, 1), 256, 0, stream>>>(fa, dummy);
  }

  GArg aa = {buf1, aw, ab, qbuf, nullptr, nullptr, nullptr, nullptr, 0};
  GArg ba = {buf1, bw, bb, kbuf, nullptr, nullptr, nullptr, nullptr, 0};
  k_gemm2<<<dim3(64, 4, 2), 256, 0, stream>>>(aa, ba);
  k_gate<<<kN, 256, 0, stream>>>(qbuf, kbuf, cw, cb, Abuf);
  k_pool_part<<<64, 256, 0, stream>>>(Abuf, buf1, ppart);
  k_pool_fin<<<1, 256, 0, stream>>>(ppart, out_w, out_b, (float*)d_out);
}

// Round 6
// 282.539 us; speedup vs baseline: 1.7516x; 1.1696x over previous
//
#include <hip/hip_runtime.h>
#include <math.h>

constexpr int kN = 4096;
constexpr int kM = 4100;
constexpr int kD = 256;
constexpr int ROWCAP = 64;
constexpr int COLCAP = 64;
constexpr int EB_CHUNKS = 16;
constexpr float kLnEps = 1e-5f;
constexpr float kScale = 0.17677669529663687f; // 1/sqrt(32)

__device__ __forceinline__ float waveSum(float v) {
#pragma unroll
  for (int m = 32; m >= 1; m >>= 1) v += __shfl_xor(v, m);
  return v;
}
__device__ __forceinline__ float waveMax(float v) {
#pragma unroll
  for (int m = 32; m >= 1; m >>= 1) v = fmaxf(v, __shfl_xor(v, m));
  return v;
}
__device__ __forceinline__ float blockSum256(float v, float* sh) {
  v = waveSum(v);
  int lane = threadIdx.x & 63, w = threadIdx.x >> 6;
  __syncthreads();
  if (lane == 0) sh[w] = v;
  __syncthreads();
  return sh[0] + sh[1] + sh[2] + sh[3];
}

// ---------------- sparse build ----------------
// one wave per row; all 16 float4 chunk-loads prefetched into registers, then
// ballot prefix-scan compaction (ascending-m).  Also extracts the 4 dense tail
// columns into compact Htail[4][kN] for coalesced use in k_pre.
__global__ __launch_bounds__(256) void k_build_csr(
    const float* __restrict__ H, int* __restrict__ row_cnt, int* __restrict__ row_idx,
    int* __restrict__ col_cnt, int* __restrict__ col_idx, float* __restrict__ col_val,
    float* __restrict__ Htail) {
  int n = (blockIdx.x * blockDim.x + threadIdx.x) >> 6;
  int lane = threadIdx.x & 63;
  const float* hrow = H + (size_t)n * kM;
  float4 v[16];
#pragma unroll
  for (int c = 0; c < 16; ++c) v[c] = *(const float4*)&hrow[c * 256 + lane * 4];
  float tv = (lane < 4) ? hrow[4096 + lane] : 0.0f;
  if (lane < 4) Htail[lane * kN + n] = tv;
  unsigned long long below = (1ull << lane) - 1ull;
  int cnt = 0;
#pragma unroll
  for (int c = 0; c < 16; ++c) {
    int mbase = c * 256 + lane * 4;
    float vv[4] = {v[c].x, v[c].y, v[c].z, v[c].w};
    unsigned long long bal[4];
#pragma unroll
    for (int j = 0; j < 4; ++j) bal[j] = __ballot(vv[j] != 0.0f);
    int pre = 0, tot = 0;
#pragma unroll
    for (int j = 0; j < 4; ++j) { pre += __popcll(bal[j] & below); tot += __popcll(bal[j]); }
    int local = 0;
#pragma unroll
    for (int j = 0; j < 4; ++j) {
      if (vv[j] != 0.0f) {
        int m = mbase + j;
        int pos = cnt + pre + local;
        if (pos < ROWCAP) row_idx[n * ROWCAP + pos] = m;
        int pc = atomicAdd(&col_cnt[m], 1);
        if (pc < COLCAP) { col_idx[m * COLCAP + pc] = n; col_val[m * COLCAP + pc] = vv[j]; }
        local++;
      }
    }
    cnt += tot;
  }
  // tail m = 4096..4099
  unsigned long long bal = __ballot(tv != 0.0f);
  if (tv != 0.0f) {
    int pos = cnt + __popcll(bal & below);
    if (pos < ROWCAP) row_idx[n * ROWCAP + pos] = 4096 + lane;
  }
  cnt += __popcll(bal);
  if (lane == 0) row_cnt[n] = cnt < ROWCAP ? cnt : ROWCAP;
}

// one wave per column: sort CSC list by row index -> deterministic order.
__global__ __launch_bounds__(256) void k_sort_csc(
    int* __restrict__ col_cnt, int* __restrict__ col_idx, float* __restrict__ col_val,
    float* __restrict__ deg) {
  int c = (blockIdx.x * blockDim.x + threadIdx.x) >> 6;
  int lane = threadIdx.x & 63;
  if (c < 4 && lane == 0) deg[kN + c] = 0.0f;  // zero deg tail (accumulated in k_pre L0)
  int cnt = col_cnt[c]; if (cnt > COLCAP) cnt = COLCAP;
  int iv = 0x7fffffff; float vv = 0.0f;
  if (lane < cnt) { iv = col_idx[c * COLCAP + lane]; vv = col_val[c * COLCAP + lane]; }
  float dsum = waveSum(vv);
  int rank = 0;
  for (int j = 0; j < 64; ++j) {
    int ivj = __shfl(iv, j);
    if (ivj < iv) rank++;
  }
  if (lane < cnt) { col_idx[c * COLCAP + rank] = iv; col_val[c * COLCAP + rank] = vv; }
  if (lane == 0) { deg[c] = dsum; col_cnt[c] = cnt; }
}

// ---------------- fused per-layer pre-pass ----------------
// blocks [0,1024): E rows (sparse CSC gather + LN) -> En
// blocks [1024,2048): per-row LN stats of X -> stats
// blocks [2048,2112): big-column (topo/stroma) partial sums from Htail -> ebpart
__global__ __launch_bounds__(256) void k_pre(
    const float* __restrict__ X, const float* __restrict__ Htail,
    const int* __restrict__ col_cnt, const int* __restrict__ col_idx,
    const float* __restrict__ col_val, float* __restrict__ deg,
    const float* __restrict__ g, const float* __restrict__ b,
    float* __restrict__ stats, float* __restrict__ En,
    float* __restrict__ ebpart, int add_deg) {
  __shared__ int sidx[4][COLCAP];
  __shared__ float sval[4][COLCAP];
  __shared__ float shr[4];
  int bid = blockIdx.x, t = threadIdx.x;
  int wq = t >> 6, lane = t & 63;
  if (bid < 1024) {
    // ---- E rows + LN ----
    int m = bid * 4 + wq;
    int cnt = col_cnt[m];
    if (lane < cnt) { sidx[wq][lane] = col_idx[m * COLCAP + lane]; sval[wq][lane] = col_val[m * COLCAP + lane]; }
    __syncthreads();
    float ax = 0.f, ay = 0.f, az = 0.f, aw4 = 0.f;
    for (int e = 0; e < cnt; ++e) {
      float vv = sval[wq][e];
      float4 xr = *(const float4*)&X[(size_t)sidx[wq][e] * kD + lane * 4];
      ax += vv * xr.x; ay += vv * xr.y; az += vv * xr.z; aw4 += vv * xr.w;
    }
    float inv = 1.0f / deg[m];
    ax *= inv; ay *= inv; az *= inv; aw4 *= inv;
    float mean = waveSum(ax + ay + az + aw4) * (1.0f / kD);
    float dx = ax - mean, dy = ay - mean, dz = az - mean, dw = aw4 - mean;
    float var = waveSum(dx * dx + dy * dy + dz * dz + dw * dw) * (1.0f / kD);
    float rstd = rsqrtf(var + kLnEps);
    float4 gv = *(const float4*)&g[lane * 4];
    float4 bv = *(const float4*)&b[lane * 4];
    float4 o;
    o.x = dx * rstd * gv.x + bv.x; o.y = dy * rstd * gv.y + bv.y;
    o.z = dz * rstd * gv.z + bv.z; o.w = dw * rstd * gv.w + bv.w;
    *(float4*)&En[(size_t)m * kD + lane * 4] = o;
  } else if (bid < 2048) {
    // ---- LN stats of X ----
    int row = (bid - 1024) * 4 + wq;
    float4 v = *(const float4*)&X[(size_t)row * kD + lane * 4];
    float s = waveSum(v.x + v.y + v.z + v.w);
    float mean = s * (1.0f / kD);
    float dx = v.x - mean, dy = v.y - mean, dz = v.z - mean, dw = v.w - mean;
    float q = waveSum(dx * dx + dy * dy + dz * dz + dw * dw);
    float rstd = rsqrtf(q * (1.0f / kD) + kLnEps);
    if (lane == 0) { stats[row * 2] = mean; stats[row * 2 + 1] = rstd; }
  } else {
    // ---- big columns partial sums (coalesced Htail) ----
    __shared__ float hv[256];
    int idx = bid - 2048;
    int chunk = idx & 15, c = idx >> 4;
    int r0 = chunk * 256;
    float v = Htail[c * kN + r0 + t];
    hv[t] = v;
    if (add_deg) {
      float ds = blockSum256(v, shr);   // values in {0,1}: integer-exact
      if (t == 0 && ds != 0.0f) atomicAdd(&deg[kN + c], ds);
    }
    __syncthreads();
    float s = 0.0f;
    for (int i = 0; i < 256; ++i) {
      float h = hv[i];
      if (h != 0.0f) s += h * X[(size_t)(r0 + i) * kD + t];
    }
    ebpart[(size_t)(c * EB_CHUNKS + chunk) * kD + t] = s;
  }
}

// ---------------- GEMM (batched via blockIdx.z; z==2 = finktail block) -------
// mode 0: C = A@W^T + bias
// mode 1: C = 0.5*relu(A@W^T + bias) + 0.5*blend
// mode 2: C = LN(A)@W^T + bias  (stats = per-row [mean,rstd]; g/b = LN affine)
struct GArg {
  const float* A; const float* W; const float* bias; float* C;
  const float* blend; const float* stats; const float* g; const float* b;
  int mode;
};
struct FArg {
  const float* part; const float* deg; const float* g; const float* b;
  const float* Wkt_w; const float* Wkt_b; const float* Wks_w; const float* Wks_b;
  float* K;
};

__global__ __launch_bounds__(256) void k_gemm2(GArg a0, GArg a1, FArg f) {
  int t = threadIdx.x;
  if (blockIdx.z == 2) {
    // ---- finktail: finalize 4 big-edge rows (LN in LDS) + Wkt/Wks proj ----
    if (blockIdx.x != 0 || blockIdx.y != 0) return;
    __shared__ float er[4][kD];
    __shared__ float sh[4];
    for (int c = 0; c < 4; ++c) {
      float s = 0.0f;
#pragma unroll
      for (int k = 0; k < EB_CHUNKS; ++k) s += f.part[(size_t)(c * EB_CHUNKS + k) * kD + t];
      s *= (1.0f / f.deg[kN + c]);
      float mean = blockSum256(s, sh) * (1.0f / kD);
      float dv = s - mean;
      float var = blockSum256(dv * dv, sh) * (1.0f / kD);
      er[c][t] = dv * rsqrtf(var + kLnEps) * f.g[t] + f.b[t];
    }
    __syncthreads();
    float a0_ = 0.f, a1_ = 0.f, a2_ = 0.f, a3_ = 0.f;
    for (int k = 0; k < kD; k += 4) {
      float4 wt = *(const float4*)&f.Wkt_w[(size_t)t * kD + k];
      float4 ws = *(const float4*)&f.Wks_w[(size_t)t * kD + k];
      float4 e0 = *(const float4*)&er[0][k];
      float4 e1 = *(const float4*)&er[1][k];
      float4 e2 = *(const float4*)&er[2][k];
      float4 e3 = *(const float4*)&er[3][k];
      a0_ += e0.x * wt.x + e0.y * wt.y + e0.z * wt.z + e0.w * wt.w;
      a1_ += e1.x * wt.x + e1.y * wt.y + e1.z * wt.z + e1.w * wt.w;
      a2_ += e2.x * wt.x + e2.y * wt.y + e2.z * wt.z + e2.w * wt.w;
      a3_ += e3.x * ws.x + e3.y * ws.y + e3.z * ws.z + e3.w * ws.w;
    }
    float bt = f.Wkt_b[t];
    f.K[(size_t)(kN + 0) * kD + t] = a0_ + bt;
    f.K[(size_t)(kN + 1) * kD + t] = a1_ + bt;
    f.K[(size_t)(kN + 2) * kD + t] = a2_ + bt;
    f.K[(size_t)(kN + 3) * kD + t] = a3_ + f.Wks_b[t];
    return;
  }
  GArg ga = blockIdx.z ? a1 : a0;
  __shared__ __align__(16) float sA[32][68];
  __shared__ __align__(16) float sW[32][68];
  int tx = t & 15, ty = t >> 4;
  int row0 = blockIdx.x * 64, col0 = blockIdx.y * 64;
  int kl = t & 31, nb = t >> 5;
  float sm_[8], sr_[8];
  if (ga.mode == 2) {
#pragma unroll
    for (int i = 0; i < 8; ++i) {
      int row = row0 + i * 8 + nb;
      sm_[i] = ga.stats[row * 2];
      sr_[i] = ga.stats[row * 2 + 1];
    }
  }
  float acc[4][4] = {};
  for (int k0 = 0; k0 < kD; k0 += 32) {
    float gk = 0.f, bk = 0.f;
    if (ga.mode == 2) { gk = ga.g[k0 + kl]; bk = ga.b[k0 + kl]; }
#pragma unroll
    for (int i = 0; i < 8; ++i) {
      int nl = i * 8 + nb;
      float v = ga.A[(size_t)(row0 + nl) * kD + k0 + kl];
      if (ga.mode == 2) v = (v - sm_[i]) * sr_[i] * gk + bk;
      sA[kl][nl] = v;
      sW[kl][nl] = ga.W[(size_t)(col0 + nl) * kD + k0 + kl];
    }
    __syncthreads();
#pragma unroll
    for (int kk = 0; kk < 32; ++kk) {
      float4 av = *(const float4*)&sA[kk][ty * 4];
      float4 wv = *(const float4*)&sW[kk][tx * 4];
      acc[0][0] += av.x * wv.x; acc[0][1] += av.x * wv.y; acc[0][2] += av.x * wv.z; acc[0][3] += av.x * wv.w;
      acc[1][0] += av.y * wv.x; acc[1][1] += av.y * wv.y; acc[1][2] += av.y * wv.z; acc[1][3] += av.y * wv.w;
      acc[2][0] += av.z * wv.x; acc[2][1] += av.z * wv.y; acc[2][2] += av.z * wv.z; acc[2][3] += av.z * wv.w;
      acc[3][0] += av.w * wv.x; acc[3][1] += av.w * wv.y; acc[3][2] += av.w * wv.z; acc[3][3] += av.w * wv.w;
    }
    __syncthreads();
  }
  int cb = col0 + tx * 4;
  float4 bv = *(const float4*)&ga.bias[cb];
#pragma unroll
  for (int i = 0; i < 4; ++i) {
    int r = row0 + ty * 4 + i;
    float4 v;
    v.x = acc[i][0] + bv.x; v.y = acc[i][1] + bv.y;
    v.z = acc[i][2] + bv.z; v.w = acc[i][3] + bv.w;
    if (ga.mode == 1) {
      float4 x0 = *(const float4*)&ga.blend[(size_t)r * kD + cb];
      v.x = 0.5f * fmaxf(v.x, 0.0f) + 0.5f * x0.x;
      v.y = 0.5f * fmaxf(v.y, 0.0f) + 0.5f * x0.y;
      v.z = 0.5f * fmaxf(v.z, 0.0f) + 0.5f * x0.z;
      v.w = 0.5f * fmaxf(v.w, 0.0f) + 0.5f * x0.w;
    }
    *(float4*)&ga.C[(size_t)r * kD + cb] = v;
  }
}

// sparse masked attention: parallel score phase.
// thread (h = t>>5, j = t&31) computes scores for edges j and j+32 via 8
// float4 loads from L2-resident kbuf; one 5-shfl max + one 5-shfl sum per
// head; P normalized into LDS; then coalesced PV pass.
__global__ __launch_bounds__(256) void k_attn(
    const float* __restrict__ q, const float* __restrict__ kbuf,
    const int* __restrict__ row_cnt, const int* __restrict__ row_idx,
    float* __restrict__ featA) {
  __shared__ int sm[ROWCAP];
  __shared__ float qls[kD];
  __shared__ float pls[8][ROWCAP];
  int n = blockIdx.x, t = threadIdx.x;
  int cnt = row_cnt[n];
  if (t < cnt) sm[t] = row_idx[n * ROWCAP + t];
  qls[t] = q[(size_t)n * kD + t];
  __syncthreads();
  int h = t >> 5, j = t & 31;
  float4 qv[8];
#pragma unroll
  for (int d4 = 0; d4 < 8; ++d4) qv[d4] = *(const float4*)&qls[h * 32 + d4 * 4];
  float s1 = 0.f, s2 = 0.f;
  if (j < cnt) {
    const float* kr = &kbuf[(size_t)sm[j] * kD + h * 32];
#pragma unroll
    for (int d4 = 0; d4 < 8; ++d4) {
      float4 kv = *(const float4*)&kr[d4 * 4];
      s1 += qv[d4].x * kv.x + qv[d4].y * kv.y + qv[d4].z * kv.z + qv[d4].w * kv.w;
    }
  }
  if (j + 32 < cnt) {
    const float* kr = &kbuf[(size_t)sm[j + 32] * kD + h * 32];
#pragma unroll
    for (int d4 = 0; d4 < 8; ++d4) {
      float4 kv = *(const float4*)&kr[d4 * 4];
      s2 += qv[d4].x * kv.x + qv[d4].y * kv.y + qv[d4].z * kv.z + qv[d4].w * kv.w;
    }
  }
  s1 *= kScale; s2 *= kScale;
  float v1 = (j < cnt) ? s1 : -3.4e38f;
  float v2 = (j + 32 < cnt) ? s2 : -3.4e38f;
  float mx = fmaxf(v1, v2);
#pragma unroll
  for (int mm = 16; mm >= 1; mm >>= 1) mx = fmaxf(mx, __shfl_xor(mx, mm));
  float p1 = (j < cnt) ? __expf(s1 - mx) : 0.0f;
  float p2 = (j + 32 < cnt) ? __expf(s2 - mx) : 0.0f;
  float ssum = p1 + p2;
#pragma unroll
  for (int mm = 16; mm >= 1; mm >>= 1) ssum += __shfl_xor(ssum, mm);
  float inv = 1.0f / ssum;
  pls[h][j] = p1 * inv;
  pls[h][j + 32] = p2 * inv;
  __syncthreads();
  float acc = 0.0f;
  for (int e = 0; e < cnt; ++e) {
    acc += pls[h][e] * kbuf[(size_t)sm[e] * kD + t];
  }
  featA[(size_t)n * kD + t] = acc;
}

// ---------------- pooling head ----------------
__global__ __launch_bounds__(256) void k_gate(
    const float* __restrict__ araw, const float* __restrict__ braw,
    const float* __restrict__ cw, const float* __restrict__ cb,
    float* __restrict__ Abuf) {
  __shared__ float sh[4];
  int n = blockIdx.x, o = threadIdx.x;
  float a = tanhf(araw[(size_t)n * kD + o]);
  float b = 1.0f / (1.0f + expf(-braw[(size_t)n * kD + o]));
  float s = blockSum256(a * b * cw[o], sh);
  if (o == 0) Abuf[n] = s + cb[0];
}

// 64 blocks; each redundantly computes the identical global max/sum over A
// (deterministic: same order in every block), then its 64-row partial pool.
__global__ __launch_bounds__(256) void k_pool_part(
    const float* __restrict__ Abuf, const float* __restrict__ feat,
    float* __restrict__ part) {
  __shared__ float sh[4];
  int b = blockIdx.x, t = threadIdx.x;
  float mx = -3.4e38f;
  for (int i = t; i < kN; i += 256) mx = fmaxf(mx, Abuf[i]);
  mx = waveMax(mx);
  int lane = t & 63, w = t >> 6;
  __syncthreads();
  if (lane == 0) sh[w] = mx;
  __syncthreads();
  mx = fmaxf(fmaxf(sh[0], sh[1]), fmaxf(sh[2], sh[3]));
  __syncthreads();
  float s = 0.0f;
  for (int i = t; i < kN; i += 256) s += expf(Abuf[i] - mx);
  s = blockSum256(s, sh);
  float inv = 1.0f / s;
  float acc = 0.0f;
  for (int r = 0; r < 64; ++r) {
    int n = b * 64 + r;
    float p = expf(Abuf[n] - mx) * inv;
    acc += p * feat[(size_t)n * kD + t];
  }
  part[(size_t)b * kD + t] = acc;
}

__global__ __launch_bounds__(256) void k_pool_fin(
    const float* __restrict__ part, const float* __restrict__ out_w,
    const float* __restrict__ out_b, float* __restrict__ out) {
  __shared__ float pooled[kD];
  int d = threadIdx.x;
  float s = 0.0f;
#pragma unroll
  for (int b = 0; b < 64; ++b) s += part[(size_t)b * kD + d];
  pooled[d] = s;
  __syncthreads();
  if (d < 4) {
    float o = out_b[d];
    for (int i = 0; i < kD; ++i) o += pooled[i] * out_w[(size_t)d * kD + i];
    out[d] = o;
  }
}

extern "C" void kernel_launch(void* const* d_in, const int* in_sizes, int n_in,
                              void* d_out, int out_size, void* d_ws, size_t ws_size,
                              hipStream_t stream) {
  (void)in_sizes; (void)n_in; (void)out_size; (void)ws_size;
  const float* X     = (const float*)d_in[0];
  const float* H     = (const float*)d_in[1];
  const float* Wq_w  = (const float*)d_in[2];
  const float* Wq_b  = (const float*)d_in[3];
  const float* Wkn_w = (const float*)d_in[4];
  const float* Wkn_b = (const float*)d_in[5];
  const float* Wkt_w = (const float*)d_in[6];
  const float* Wkt_b = (const float*)d_in[7];
  const float* Wks_w = (const float*)d_in[8];
  const float* Wks_b = (const float*)d_in[9];
  const float* fc_w  = (const float*)d_in[10];
  const float* fc_b  = (const float*)d_in[11];
  const float* ln_g  = (const float*)d_in[12];
  const float* ln_b  = (const float*)d_in[13];
  const float* aw    = (const float*)d_in[14];
  const float* ab    = (const float*)d_in[15];
  const float* bw    = (const float*)d_in[16];
  const float* bb    = (const float*)d_in[17];
  const float* cw    = (const float*)d_in[18];
  const float* cb    = (const float*)d_in[19];
  const float* out_w = (const float*)d_in[20];
  const float* out_b = (const float*)d_in[21];

  char* p = (char*)d_ws;
  auto alloc = [&](size_t bytes) -> void* {
    void* r = (void*)p;
    p += (bytes + 255) & ~(size_t)255;
    return r;
  };
  int*   row_cnt = (int*)alloc(kN * 4);
  int*   row_idx = (int*)alloc((size_t)kN * ROWCAP * 4);
  int*   col_cnt = (int*)alloc(kN * 4);
  int*   col_idx = (int*)alloc((size_t)kN * COLCAP * 4);
  float* col_val = (float*)alloc((size_t)kN * COLCAP * 4);
  float* Htail   = (float*)alloc((size_t)4 * kN * 4);
  float* deg     = (float*)alloc(kM * 4);
  float* stats   = (float*)alloc((size_t)kN * 2 * 4);
  float* En      = (float*)alloc((size_t)kM * kD * 4);
  float* qbuf    = (float*)alloc((size_t)kN * kD * 4);
  float* kbuf    = (float*)alloc((size_t)kM * kD * 4);
  float* featA   = (float*)alloc((size_t)kN * kD * 4);
  float* buf0    = (float*)alloc((size_t)kN * kD * 4);
  float* buf1    = (float*)alloc((size_t)kN * kD * 4);
  float* ebpart  = (float*)alloc((size_t)4 * EB_CHUNKS * kD * 4);
  float* Abuf    = (float*)alloc(kN * 4);
  float* ppart   = (float*)alloc(64 * kD * 4);

  hipMemsetAsync(col_cnt, 0, kN * 4, stream);
  k_build_csr<<<kN / 4, 256, 0, stream>>>(H, row_cnt, row_idx, col_cnt, col_idx, col_val, Htail);
  k_sort_csc<<<kN / 4, 256, 0, stream>>>(col_cnt, col_idx, col_val, deg);

  FArg fdummy = {};
  GArg gdummy = {};
  for (int layer = 0; layer < 2; ++layer) {
    const float* Xc = layer ? buf0 : X;
    float* Xout = layer ? buf1 : buf0;
    size_t wo = (size_t)layer * kD * kD;
    size_t bo = (size_t)layer * kD;
    k_pre<<<2112, 256, 0, stream>>>(Xc, Htail, col_cnt, col_idx, col_val, deg,
                                    ln_g + bo, ln_b + bo, stats, En, ebpart, layer == 0);
    GArg qa = {Xc, Wq_w + wo, Wq_b + bo, qbuf, nullptr, stats, ln_g + bo, ln_b + bo, 2};
    GArg ka = {En, Wkn_w + wo, Wkn_b + bo, kbuf, nullptr, nullptr, nullptr, nullptr, 0};
    FArg fk = {ebpart, deg, ln_g + bo, ln_b + bo,
               Wkt_w + wo, Wkt_b + bo, Wks_w + wo, Wks_b + bo, kbuf};
    k_gemm2<<<dim3(64, 4, 3), 256, 0, stream>>>(qa, ka, fk);
    k_attn<<<kN, 256, 0, stream>>>(qbuf, kbuf, row_cnt, row_idx, featA);
    GArg fa = {featA, fc_w + wo, fc_b + bo, Xout, Xc, nullptr, nullptr, nullptr, 1};
    k_gemm2<<<dim3(64, 4, 1), 256, 0, stream>>>(fa, gdummy, fdummy);
  }

  GArg aa = {buf1, aw, ab, qbuf, nullptr, nullptr, nullptr, nullptr, 0};
  GArg ba = {buf1, bw, bb, kbuf, nullptr, nullptr, nullptr, nullptr, 0};
  k_gemm2<<<dim3(64, 4, 2), 256, 0, stream>>>(aa, ba, fdummy);
  k_gate<<<kN, 256, 0, stream>>>(qbuf, kbuf, cw, cb, Abuf);
  k_pool_part<<<64, 256, 0, stream>>>(Abuf, buf1, ppart);
  k_pool_fin<<<1, 256, 0, stream>>>(ppart, out_w, out_b, (float*)d_out);
}

// Round 7
// 280.679 us; speedup vs baseline: 1.7632x; 1.0066x over previous
//
#include <hip/hip_runtime.h>
#include <math.h>

constexpr int kN = 4096;
constexpr int kM = 4100;
constexpr int kD = 256;
constexpr int ROWCAP = 64;
constexpr int COLCAP = 64;
constexpr int EB_CHUNKS = 16;
constexpr float kLnEps = 1e-5f;
constexpr float kScale = 0.17677669529663687f; // 1/sqrt(32)

__device__ __forceinline__ float waveSum(float v) {
#pragma unroll
  for (int m = 32; m >= 1; m >>= 1) v += __shfl_xor(v, m);
  return v;
}
__device__ __forceinline__ float waveMax(float v) {
#pragma unroll
  for (int m = 32; m >= 1; m >>= 1) v = fmaxf(v, __shfl_xor(v, m));
  return v;
}
__device__ __forceinline__ float blockSum256(float v, float* sh) {
  v = waveSum(v);
  int lane = threadIdx.x & 63, w = threadIdx.x >> 6;
  __syncthreads();
  if (lane == 0) sh[w] = v;
  __syncthreads();
  return sh[0] + sh[1] + sh[2] + sh[3];
}

// ---------------- sparse build ----------------
// one wave per row; all 16 float4 chunk-loads prefetched into registers, then
// ballot prefix-scan compaction (ascending-m).  Also extracts the 4 dense tail
// columns into compact Htail[4][kN].
__global__ __launch_bounds__(256) void k_build_csr(
    const float* __restrict__ H, int* __restrict__ row_cnt, int* __restrict__ row_idx,
    int* __restrict__ col_cnt, int* __restrict__ col_idx, float* __restrict__ col_val,
    float* __restrict__ Htail) {
  int n = (blockIdx.x * blockDim.x + threadIdx.x) >> 6;
  int lane = threadIdx.x & 63;
  const float* hrow = H + (size_t)n * kM;
  float4 v[16];
#pragma unroll
  for (int c = 0; c < 16; ++c) v[c] = *(const float4*)&hrow[c * 256 + lane * 4];
  float tv = (lane < 4) ? hrow[4096 + lane] : 0.0f;
  if (lane < 4) Htail[lane * kN + n] = tv;
  unsigned long long below = (1ull << lane) - 1ull;
  int cnt = 0;
#pragma unroll
  for (int c = 0; c < 16; ++c) {
    int mbase = c * 256 + lane * 4;
    float vv[4] = {v[c].x, v[c].y, v[c].z, v[c].w};
    unsigned long long bal[4];
#pragma unroll
    for (int j = 0; j < 4; ++j) bal[j] = __ballot(vv[j] != 0.0f);
    int pre = 0, tot = 0;
#pragma unroll
    for (int j = 0; j < 4; ++j) { pre += __popcll(bal[j] & below); tot += __popcll(bal[j]); }
    int local = 0;
#pragma unroll
    for (int j = 0; j < 4; ++j) {
      if (vv[j] != 0.0f) {
        int m = mbase + j;
        int pos = cnt + pre + local;
        if (pos < ROWCAP) row_idx[n * ROWCAP + pos] = m;
        int pc = atomicAdd(&col_cnt[m], 1);
        if (pc < COLCAP) { col_idx[m * COLCAP + pc] = n; col_val[m * COLCAP + pc] = vv[j]; }
        local++;
      }
    }
    cnt += tot;
  }
  // tail m = 4096..4099
  unsigned long long bal = __ballot(tv != 0.0f);
  if (tv != 0.0f) {
    int pos = cnt + __popcll(bal & below);
    if (pos < ROWCAP) row_idx[n * ROWCAP + pos] = 4096 + lane;
  }
  cnt += __popcll(bal);
  if (lane == 0) row_cnt[n] = cnt < ROWCAP ? cnt : ROWCAP;
}

// one wave per column: sort CSC list by row index -> deterministic order.
__global__ __launch_bounds__(256) void k_sort_csc(
    int* __restrict__ col_cnt, int* __restrict__ col_idx, float* __restrict__ col_val,
    float* __restrict__ deg) {
  int c = (blockIdx.x * blockDim.x + threadIdx.x) >> 6;
  int lane = threadIdx.x & 63;
  if (c < 4 && lane == 0) deg[kN + c] = 0.0f;  // zero deg tail (accumulated in k_pre L0)
  int cnt = col_cnt[c]; if (cnt > COLCAP) cnt = COLCAP;
  int iv = 0x7fffffff; float vv = 0.0f;
  if (lane < cnt) { iv = col_idx[c * COLCAP + lane]; vv = col_val[c * COLCAP + lane]; }
  float dsum = waveSum(vv);
  int rank = 0;
  for (int j = 0; j < 64; ++j) {
    int ivj = __shfl(iv, j);
    if (ivj < iv) rank++;
  }
  if (lane < cnt) { col_idx[c * COLCAP + rank] = iv; col_val[c * COLCAP + rank] = vv; }
  if (lane == 0) { deg[c] = dsum; col_cnt[c] = cnt; }
}

// ---------------- fused per-layer pre-pass ----------------
// blocks [0,1024): E rows (sparse CSC gather + LN) -> En
// blocks [1024,2048): per-row LN stats of X -> stats
// blocks [2048,2112): big-column (topo/stroma) partial sums from Htail -> ebpart
__global__ __launch_bounds__(256) void k_pre(
    const float* __restrict__ X, const float* __restrict__ Htail,
    const int* __restrict__ col_cnt, const int* __restrict__ col_idx,
    const float* __restrict__ col_val, float* __restrict__ deg,
    const float* __restrict__ g, const float* __restrict__ b,
    float* __restrict__ stats, float* __restrict__ En,
    float* __restrict__ ebpart, int add_deg) {
  __shared__ int sidx[4][COLCAP];
  __shared__ float sval[4][COLCAP];
  __shared__ float shr[4];
  int bid = blockIdx.x, t = threadIdx.x;
  int wq = t >> 6, lane = t & 63;
  if (bid < 1024) {
    // ---- E rows + LN (2-way unrolled gather, 2 independent acc chains) ----
    int m = bid * 4 + wq;
    int cnt = col_cnt[m];
    if (lane < cnt) { sidx[wq][lane] = col_idx[m * COLCAP + lane]; sval[wq][lane] = col_val[m * COLCAP + lane]; }
    __syncthreads();
    float ax0 = 0.f, ay0 = 0.f, az0 = 0.f, aw0 = 0.f;
    float ax1 = 0.f, ay1 = 0.f, az1 = 0.f, aw1 = 0.f;
    int e = 0;
    for (; e + 1 < cnt; e += 2) {
      float v0 = sval[wq][e], v1 = sval[wq][e + 1];
      float4 x0 = *(const float4*)&X[(size_t)sidx[wq][e] * kD + lane * 4];
      float4 x1 = *(const float4*)&X[(size_t)sidx[wq][e + 1] * kD + lane * 4];
      ax0 += v0 * x0.x; ay0 += v0 * x0.y; az0 += v0 * x0.z; aw0 += v0 * x0.w;
      ax1 += v1 * x1.x; ay1 += v1 * x1.y; az1 += v1 * x1.z; aw1 += v1 * x1.w;
    }
    if (e < cnt) {
      float v0 = sval[wq][e];
      float4 x0 = *(const float4*)&X[(size_t)sidx[wq][e] * kD + lane * 4];
      ax0 += v0 * x0.x; ay0 += v0 * x0.y; az0 += v0 * x0.z; aw0 += v0 * x0.w;
    }
    float ax = ax0 + ax1, ay = ay0 + ay1, az = az0 + az1, aw4 = aw0 + aw1;
    float inv = 1.0f / deg[m];
    ax *= inv; ay *= inv; az *= inv; aw4 *= inv;
    float mean = waveSum(ax + ay + az + aw4) * (1.0f / kD);
    float dx = ax - mean, dy = ay - mean, dz = az - mean, dw = aw4 - mean;
    float var = waveSum(dx * dx + dy * dy + dz * dz + dw * dw) * (1.0f / kD);
    float rstd = rsqrtf(var + kLnEps);
    float4 gv = *(const float4*)&g[lane * 4];
    float4 bv = *(const float4*)&b[lane * 4];
    float4 o;
    o.x = dx * rstd * gv.x + bv.x; o.y = dy * rstd * gv.y + bv.y;
    o.z = dz * rstd * gv.z + bv.z; o.w = dw * rstd * gv.w + bv.w;
    *(float4*)&En[(size_t)m * kD + lane * 4] = o;
  } else if (bid < 2048) {
    // ---- LN stats of X ----
    int row = (bid - 1024) * 4 + wq;
    float4 v = *(const float4*)&X[(size_t)row * kD + lane * 4];
    float s = waveSum(v.x + v.y + v.z + v.w);
    float mean = s * (1.0f / kD);
    float dx = v.x - mean, dy = v.y - mean, dz = v.z - mean, dw = v.w - mean;
    float q = waveSum(dx * dx + dy * dy + dz * dz + dw * dw);
    float rstd = rsqrtf(q * (1.0f / kD) + kLnEps);
    if (lane == 0) { stats[row * 2] = mean; stats[row * 2 + 1] = rstd; }
  } else {
    // ---- big columns partial sums (coalesced Htail) ----
    __shared__ float hv[256];
    int idx = bid - 2048;
    int chunk = idx & 15, c = idx >> 4;
    int r0 = chunk * 256;
    float v = Htail[c * kN + r0 + t];
    hv[t] = v;
    if (add_deg) {
      float ds = blockSum256(v, shr);   // values in {0,1}: integer-exact
      if (t == 0 && ds != 0.0f) atomicAdd(&deg[kN + c], ds);
    }
    __syncthreads();
    float s = 0.0f;
    for (int i = 0; i < 256; ++i) {
      float h = hv[i];
      if (h != 0.0f) s += h * X[(size_t)(r0 + i) * kD + t];
    }
    ebpart[(size_t)(c * EB_CHUNKS + chunk) * kD + t] = s;
  }
}

// ---------------- GEMM (batched via blockIdx.z; z==2 = finktail block) -------
// mode 0: C = A@W^T + bias
// mode 1: C = 0.5*relu(A@W^T + bias) + 0.5*blend
// mode 2: C = LN(A)@W^T + bias  (stats = per-row [mean,rstd]; g/b = LN affine)
struct GArg {
  const float* A; const float* W; const float* bias; float* C;
  const float* blend; const float* stats; const float* g; const float* b;
  int mode;
};
struct FArg {
  const float* part; const float* deg; const float* g; const float* b;
  const float* Wkt_w; const float* Wkt_b; const float* Wks_w; const float* Wks_b;
  float* K;
};

__global__ __launch_bounds__(256) void k_gemm2(GArg a0, GArg a1, FArg f) {
  int t = threadIdx.x;
  if (blockIdx.z == 2) {
    // ---- finktail: finalize 4 big-edge rows (LN in LDS) + Wkt/Wks proj ----
    if (blockIdx.x != 0 || blockIdx.y != 0) return;
    __shared__ float er[4][kD];
    __shared__ float sh[4];
    for (int c = 0; c < 4; ++c) {
      float s = 0.0f;
#pragma unroll
      for (int k = 0; k < EB_CHUNKS; ++k) s += f.part[(size_t)(c * EB_CHUNKS + k) * kD + t];
      s *= (1.0f / f.deg[kN + c]);
      float mean = blockSum256(s, sh) * (1.0f / kD);
      float dv = s - mean;
      float var = blockSum256(dv * dv, sh) * (1.0f / kD);
      er[c][t] = dv * rsqrtf(var + kLnEps) * f.g[t] + f.b[t];
    }
    __syncthreads();
    float a0_ = 0.f, a1_ = 0.f, a2_ = 0.f, a3_ = 0.f;
    for (int k = 0; k < kD; k += 4) {
      float4 wt = *(const float4*)&f.Wkt_w[(size_t)t * kD + k];
      float4 ws = *(const float4*)&f.Wks_w[(size_t)t * kD + k];
      float4 e0 = *(const float4*)&er[0][k];
      float4 e1 = *(const float4*)&er[1][k];
      float4 e2 = *(const float4*)&er[2][k];
      float4 e3 = *(const float4*)&er[3][k];
      a0_ += e0.x * wt.x + e0.y * wt.y + e0.z * wt.z + e0.w * wt.w;
      a1_ += e1.x * wt.x + e1.y * wt.y + e1.z * wt.z + e1.w * wt.w;
      a2_ += e2.x * wt.x + e2.y * wt.y + e2.z * wt.z + e2.w * wt.w;
      a3_ += e3.x * ws.x + e3.y * ws.y + e3.z * ws.z + e3.w * ws.w;
    }
    float bt = f.Wkt_b[t];
    f.K[(size_t)(kN + 0) * kD + t] = a0_ + bt;
    f.K[(size_t)(kN + 1) * kD + t] = a1_ + bt;
    f.K[(size_t)(kN + 2) * kD + t] = a2_ + bt;
    f.K[(size_t)(kN + 3) * kD + t] = a3_ + f.Wks_b[t];
    return;
  }
  GArg ga = blockIdx.z ? a1 : a0;
  __shared__ __align__(16) float sA[32][68];
  __shared__ __align__(16) float sW[32][68];
  int tx = t & 15, ty = t >> 4;
  int row0 = blockIdx.x * 64, col0 = blockIdx.y * 64;
  int kl = t & 31, nb = t >> 5;
  float sm_[8], sr_[8];
  if (ga.mode == 2) {
#pragma unroll
    for (int i = 0; i < 8; ++i) {
      int row = row0 + i * 8 + nb;
      sm_[i] = ga.stats[row * 2];
      sr_[i] = ga.stats[row * 2 + 1];
    }
  }
  float acc[4][4] = {};
  for (int k0 = 0; k0 < kD; k0 += 32) {
    float gk = 0.f, bk = 0.f;
    if (ga.mode == 2) { gk = ga.g[k0 + kl]; bk = ga.b[k0 + kl]; }
#pragma unroll
    for (int i = 0; i < 8; ++i) {
      int nl = i * 8 + nb;
      float v = ga.A[(size_t)(row0 + nl) * kD + k0 + kl];
      if (ga.mode == 2) v = (v - sm_[i]) * sr_[i] * gk + bk;
      sA[kl][nl] = v;
      sW[kl][nl] = ga.W[(size_t)(col0 + nl) * kD + k0 + kl];
    }
    __syncthreads();
#pragma unroll
    for (int kk = 0; kk < 32; ++kk) {
      float4 av = *(const float4*)&sA[kk][ty * 4];
      float4 wv = *(const float4*)&sW[kk][tx * 4];
      acc[0][0] += av.x * wv.x; acc[0][1] += av.x * wv.y; acc[0][2] += av.x * wv.z; acc[0][3] += av.x * wv.w;
      acc[1][0] += av.y * wv.x; acc[1][1] += av.y * wv.y; acc[1][2] += av.y * wv.z; acc[1][3] += av.y * wv.w;
      acc[2][0] += av.z * wv.x; acc[2][1] += av.z * wv.y; acc[2][2] += av.z * wv.z; acc[2][3] += av.z * wv.w;
      acc[3][0] += av.w * wv.x; acc[3][1] += av.w * wv.y; acc[3][2] += av.w * wv.z; acc[3][3] += av.w * wv.w;
    }
    __syncthreads();
  }
  int cb = col0 + tx * 4;
  float4 bv = *(const float4*)&ga.bias[cb];
#pragma unroll
  for (int i = 0; i < 4; ++i) {
    int r = row0 + ty * 4 + i;
    float4 v;
    v.x = acc[i][0] + bv.x; v.y = acc[i][1] + bv.y;
    v.z = acc[i][2] + bv.z; v.w = acc[i][3] + bv.w;
    if (ga.mode == 1) {
      float4 x0 = *(const float4*)&ga.blend[(size_t)r * kD + cb];
      v.x = 0.5f * fmaxf(v.x, 0.0f) + 0.5f * x0.x;
      v.y = 0.5f * fmaxf(v.y, 0.0f) + 0.5f * x0.y;
      v.z = 0.5f * fmaxf(v.z, 0.0f) + 0.5f * x0.z;
      v.w = 0.5f * fmaxf(v.w, 0.0f) + 0.5f * x0.w;
    }
    *(float4*)&ga.C[(size_t)r * kD + cb] = v;
  }
}

// fused a/b projections + gated partial: gpart[y][n] = sum_{col in y-tile}
// tanh(a)*sigmoid(b)*cw[col].  One A-staging for both GEMMs.
__global__ __launch_bounds__(256) void k_gemm_ab(
    const float* __restrict__ A, const float* __restrict__ Wa,
    const float* __restrict__ ba, const float* __restrict__ Wb,
    const float* __restrict__ bbv_, const float* __restrict__ cw,
    float* __restrict__ gpart) {
  __shared__ __align__(16) float sA[32][68];
  __shared__ __align__(16) float sWa[32][68];
  __shared__ __align__(16) float sWb[32][68];
  __shared__ float sred[64][17];
  int t = threadIdx.x;
  int tx = t & 15, ty = t >> 4;
  int row0 = blockIdx.x * 64, col0 = blockIdx.y * 64;
  int kl = t & 31, nb = t >> 5;
  float acca[4][4] = {}, accb[4][4] = {};
  for (int k0 = 0; k0 < kD; k0 += 32) {
#pragma unroll
    for (int i = 0; i < 8; ++i) {
      int nl = i * 8 + nb;
      sA[kl][nl]  = A[(size_t)(row0 + nl) * kD + k0 + kl];
      sWa[kl][nl] = Wa[(size_t)(col0 + nl) * kD + k0 + kl];
      sWb[kl][nl] = Wb[(size_t)(col0 + nl) * kD + k0 + kl];
    }
    __syncthreads();
#pragma unroll
    for (int kk = 0; kk < 32; ++kk) {
      float4 av = *(const float4*)&sA[kk][ty * 4];
      float4 wa = *(const float4*)&sWa[kk][tx * 4];
      float4 wb = *(const float4*)&sWb[kk][tx * 4];
      acca[0][0] += av.x * wa.x; acca[0][1] += av.x * wa.y; acca[0][2] += av.x * wa.z; acca[0][3] += av.x * wa.w;
      acca[1][0] += av.y * wa.x; acca[1][1] += av.y * wa.y; acca[1][2] += av.y * wa.z; acca[1][3] += av.y * wa.w;
      acca[2][0] += av.z * wa.x; acca[2][1] += av.z * wa.y; acca[2][2] += av.z * wa.z; acca[2][3] += av.z * wa.w;
      acca[3][0] += av.w * wa.x; acca[3][1] += av.w * wa.y; acca[3][2] += av.w * wa.z; acca[3][3] += av.w * wa.w;
      accb[0][0] += av.x * wb.x; accb[0][1] += av.x * wb.y; accb[0][2] += av.x * wb.z; accb[0][3] += av.x * wb.w;
      accb[1][0] += av.y * wb.x; accb[1][1] += av.y * wb.y; accb[1][2] += av.y * wb.z; accb[1][3] += av.y * wb.w;
      accb[2][0] += av.z * wb.x; accb[2][1] += av.z * wb.y; accb[2][2] += av.z * wb.z; accb[2][3] += av.z * wb.w;
      accb[3][0] += av.w * wb.x; accb[3][1] += av.w * wb.y; accb[3][2] += av.w * wb.z; accb[3][3] += av.w * wb.w;
    }
    __syncthreads();
  }
  int cb4 = col0 + tx * 4;
  float4 bav = *(const float4*)&ba[cb4];
  float4 bbv = *(const float4*)&bbv_[cb4];
  float4 cwv = *(const float4*)&cw[cb4];
#pragma unroll
  for (int i = 0; i < 4; ++i) {
    float a0 = tanhf(acca[i][0] + bav.x), a1 = tanhf(acca[i][1] + bav.y);
    float a2 = tanhf(acca[i][2] + bav.z), a3 = tanhf(acca[i][3] + bav.w);
    float b0 = 1.0f / (1.0f + __expf(-(accb[i][0] + bbv.x)));
    float b1 = 1.0f / (1.0f + __expf(-(accb[i][1] + bbv.y)));
    float b2 = 1.0f / (1.0f + __expf(-(accb[i][2] + bbv.z)));
    float b3 = 1.0f / (1.0f + __expf(-(accb[i][3] + bbv.w)));
    sred[ty * 4 + i][tx] = a0 * b0 * cwv.x + a1 * b1 * cwv.y + a2 * b2 * cwv.z + a3 * b3 * cwv.w;
  }
  __syncthreads();
  if (t < 64) {
    float s = 0.0f;
#pragma unroll
    for (int j = 0; j < 16; ++j) s += sred[t][j];
    gpart[(size_t)blockIdx.y * kN + row0 + t] = s;
  }
}

// sparse masked attention: parallel score phase + 4-way-unrolled PV.
__global__ __launch_bounds__(256) void k_attn(
    const float* __restrict__ q, const float* __restrict__ kbuf,
    const int* __restrict__ row_cnt, const int* __restrict__ row_idx,
    float* __restrict__ featA) {
  __shared__ int sm[ROWCAP];
  __shared__ float qls[kD];
  __shared__ float pls[8][ROWCAP];
  int n = blockIdx.x, t = threadIdx.x;
  int cnt = row_cnt[n];
  if (t < cnt) sm[t] = row_idx[n * ROWCAP + t];
  qls[t] = q[(size_t)n * kD + t];
  __syncthreads();
  int h = t >> 5, j = t & 31;
  float4 qv[8];
#pragma unroll
  for (int d4 = 0; d4 < 8; ++d4) qv[d4] = *(const float4*)&qls[h * 32 + d4 * 4];
  float s1 = 0.f, s2 = 0.f;
  if (j < cnt) {
    const float* kr = &kbuf[(size_t)sm[j] * kD + h * 32];
#pragma unroll
    for (int d4 = 0; d4 < 8; ++d4) {
      float4 kv = *(const float4*)&kr[d4 * 4];
      s1 += qv[d4].x * kv.x + qv[d4].y * kv.y + qv[d4].z * kv.z + qv[d4].w * kv.w;
    }
  }
  if (j + 32 < cnt) {
    const float* kr = &kbuf[(size_t)sm[j + 32] * kD + h * 32];
#pragma unroll
    for (int d4 = 0; d4 < 8; ++d4) {
      float4 kv = *(const float4*)&kr[d4 * 4];
      s2 += qv[d4].x * kv.x + qv[d4].y * kv.y + qv[d4].z * kv.z + qv[d4].w * kv.w;
    }
  }
  s1 *= kScale; s2 *= kScale;
  float v1 = (j < cnt) ? s1 : -3.4e38f;
  float v2 = (j + 32 < cnt) ? s2 : -3.4e38f;
  float mx = fmaxf(v1, v2);
#pragma unroll
  for (int mm = 16; mm >= 1; mm >>= 1) mx = fmaxf(mx, __shfl_xor(mx, mm));
  float p1 = (j < cnt) ? __expf(s1 - mx) : 0.0f;
  float p2 = (j + 32 < cnt) ? __expf(s2 - mx) : 0.0f;
  float ssum = p1 + p2;
#pragma unroll
  for (int mm = 16; mm >= 1; mm >>= 1) ssum += __shfl_xor(ssum, mm);
  float inv = 1.0f / ssum;
  pls[h][j] = p1 * inv;
  pls[h][j + 32] = p2 * inv;
  __syncthreads();
  const float* kb = kbuf + t;
  float ac0 = 0.f, ac1 = 0.f, ac2 = 0.f, ac3 = 0.f;
  int e = 0;
  for (; e + 3 < cnt; e += 4) {
    ac0 += pls[h][e]     * kb[(size_t)sm[e] * kD];
    ac1 += pls[h][e + 1] * kb[(size_t)sm[e + 1] * kD];
    ac2 += pls[h][e + 2] * kb[(size_t)sm[e + 2] * kD];
    ac3 += pls[h][e + 3] * kb[(size_t)sm[e + 3] * kD];
  }
  for (; e < cnt; ++e) ac0 += pls[h][e] * kb[(size_t)sm[e] * kD];
  featA[(size_t)n * kD + t] = (ac0 + ac1) + (ac2 + ac3);
}

// ---------------- pooling head ----------------
// 64 blocks; each redundantly computes the identical global max/sum over
// A[n] = sum_y gpart[y][n] + cb (deterministic), then its 64-row partial pool.
__global__ __launch_bounds__(256) void k_pool_part(
    const float* __restrict__ gpart, const float* __restrict__ cb,
    const float* __restrict__ feat, float* __restrict__ part) {
  __shared__ float sh[4];
  int b = blockIdx.x, t = threadIdx.x;
  float cb0 = cb[0];
  float mx = -3.4e38f;
  for (int i = t; i < kN; i += 256) {
    float a = gpart[i] + gpart[kN + i] + gpart[2 * kN + i] + gpart[3 * kN + i] + cb0;
    mx = fmaxf(mx, a);
  }
  mx = waveMax(mx);
  int lane = t & 63, w = t >> 6;
  __syncthreads();
  if (lane == 0) sh[w] = mx;
  __syncthreads();
  mx = fmaxf(fmaxf(sh[0], sh[1]), fmaxf(sh[2], sh[3]));
  __syncthreads();
  float s = 0.0f;
  for (int i = t; i < kN; i += 256) {
    float a = gpart[i] + gpart[kN + i] + gpart[2 * kN + i] + gpart[3 * kN + i] + cb0;
    s += expf(a - mx);
  }
  s = blockSum256(s, sh);
  float inv = 1.0f / s;
  float acc = 0.0f;
  for (int r = 0; r < 64; ++r) {
    int n = b * 64 + r;
    float a = gpart[n] + gpart[kN + n] + gpart[2 * kN + n] + gpart[3 * kN + n] + cb0;
    float p = expf(a - mx) * inv;
    acc += p * feat[(size_t)n * kD + t];
  }
  part[(size_t)b * kD + t] = acc;
}

__global__ __launch_bounds__(256) void k_pool_fin(
    const float* __restrict__ part, const float* __restrict__ out_w,
    const float* __restrict__ out_b, float* __restrict__ out) {
  __shared__ float pooled[kD];
  int d = threadIdx.x;
  float s = 0.0f;
#pragma unroll
  for (int b = 0; b < 64; ++b) s += part[(size_t)b * kD + d];
  pooled[d] = s;
  __syncthreads();
  if (d < 4) {
    float o = out_b[d];
    for (int i = 0; i < kD; ++i) o += pooled[i] * out_w[(size_t)d * kD + i];
    out[d] = o;
  }
}

extern "C" void kernel_launch(void* const* d_in, const int* in_sizes, int n_in,
                              void* d_out, int out_size, void* d_ws, size_t ws_size,
                              hipStream_t stream) {
  (void)in_sizes; (void)n_in; (void)out_size; (void)ws_size;
  const float* X     = (const float*)d_in[0];
  const float* H     = (const float*)d_in[1];
  const float* Wq_w  = (const float*)d_in[2];
  const float* Wq_b  = (const float*)d_in[3];
  const float* Wkn_w = (const float*)d_in[4];
  const float* Wkn_b = (const float*)d_in[5];
  const float* Wkt_w = (const float*)d_in[6];
  const float* Wkt_b = (const float*)d_in[7];
  const float* Wks_w = (const float*)d_in[8];
  const float* Wks_b = (const float*)d_in[9];
  const float* fc_w  = (const float*)d_in[10];
  const float* fc_b  = (const float*)d_in[11];
  const float* ln_g  = (const float*)d_in[12];
  const float* ln_b  = (const float*)d_in[13];
  const float* aw    = (const float*)d_in[14];
  const float* ab    = (const float*)d_in[15];
  const float* bw    = (const float*)d_in[16];
  const float* bb    = (const float*)d_in[17];
  const float* cw    = (const float*)d_in[18];
  const float* cb    = (const float*)d_in[19];
  const float* out_w = (const float*)d_in[20];
  const float* out_b = (const float*)d_in[21];

  char* p = (char*)d_ws;
  auto alloc = [&](size_t bytes) -> void* {
    void* r = (void*)p;
    p += (bytes + 255) & ~(size_t)255;
    return r;
  };
  int*   row_cnt = (int*)alloc(kN * 4);
  int*   row_idx = (int*)alloc((size_t)kN * ROWCAP * 4);
  int*   col_cnt = (int*)alloc(kN * 4);
  int*   col_idx = (int*)alloc((size_t)kN * COLCAP * 4);
  float* col_val = (float*)alloc((size_t)kN * COLCAP * 4);
  float* Htail   = (float*)alloc((size_t)4 * kN * 4);
  float* deg     = (float*)alloc(kM * 4);
  float* stats   = (float*)alloc((size_t)kN * 2 * 4);
  float* En      = (float*)alloc((size_t)kM * kD * 4);
  float* qbuf    = (float*)alloc((size_t)kN * kD * 4);
  float* kbuf    = (float*)alloc((size_t)kM * kD * 4);
  float* featA   = (float*)alloc((size_t)kN * kD * 4);
  float* buf0    = (float*)alloc((size_t)kN * kD * 4);
  float* buf1    = (float*)alloc((size_t)kN * kD * 4);
  float* ebpart  = (float*)alloc((size_t)4 * EB_CHUNKS * kD * 4);
  float* gpart   = (float*)alloc((size_t)4 * kN * 4);
  float* ppart   = (float*)alloc(64 * kD * 4);

  hipMemsetAsync(col_cnt, 0, kN * 4, stream);
  k_build_csr<<<kN / 4, 256, 0, stream>>>(H, row_cnt, row_idx, col_cnt, col_idx, col_val, Htail);
  k_sort_csc<<<kN / 4, 256, 0, stream>>>(col_cnt, col_idx, col_val, deg);

  FArg fdummy = {};
  GArg gdummy = {};
  for (int layer = 0; layer < 2; ++layer) {
    const float* Xc = layer ? buf0 : X;
    float* Xout = layer ? buf1 : buf0;
    size_t wo = (size_t)layer * kD * kD;
    size_t bo = (size_t)layer * kD;
    k_pre<<<2112, 256, 0, stream>>>(Xc, Htail, col_cnt, col_idx, col_val, deg,
                                    ln_g + bo, ln_b + bo, stats, En, ebpart, layer == 0);
    GArg qa = {Xc, Wq_w + wo, Wq_b + bo, qbuf, nullptr, stats, ln_g + bo, ln_b + bo, 2};
    GArg ka = {En, Wkn_w + wo, Wkn_b + bo, kbuf, nullptr, nullptr, nullptr, nullptr, 0};
    FArg fk = {ebpart, deg, ln_g + bo, ln_b + bo,
               Wkt_w + wo, Wkt_b + bo, Wks_w + wo, Wks_b + bo, kbuf};
    k_gemm2<<<dim3(64, 4, 3), 256, 0, stream>>>(qa, ka, fk);
    k_attn<<<kN, 256, 0, stream>>>(qbuf, kbuf, row_cnt, row_idx, featA);
    GArg fa = {featA, fc_w + wo, fc_b + bo, Xout, Xc, nullptr, nullptr, nullptr, 1};
    k_gemm2<<<dim3(64, 4, 1), 256, 0, stream>>>(fa, gdummy, fdummy);
  }

  k_gemm_ab<<<dim3(64, 4), 256, 0, stream>>>(buf1, aw, ab, bw, bb, cw, gpart);
  k_pool_part<<<64, 256, 0, stream>>>(gpart, cb, buf1, ppart);
  k_pool_fin<<<1, 256, 0, stream>>>(ppart, out_w, out_b, (float*)d_out);
}